// Round 6
// baseline (405.961 us; speedup 1.0000x reference)
//
#include <hip/hip_runtime.h>

#define S_ 2048
#define D_ 1024
#define B_ 2
#define H_ 16
#define DK_ 64
#define HID_ 4096

typedef unsigned short u16;
typedef __attribute__((ext_vector_type(8))) short short8;
typedef __attribute__((ext_vector_type(4))) short s16x4;
typedef __attribute__((ext_vector_type(4))) float f32x4;

// frag-linear slot with bank-spreading XOR: panel of 64 slots x 16B
#define SLOT(q16, r16) (((q16) * 16) + ((r16) ^ (q16)))

__device__ __forceinline__ float bf2f(u16 u) {
  return __uint_as_float(((unsigned int)u) << 16);
}
__device__ __forceinline__ u16 f2bf(float f) {
  unsigned int x = __float_as_uint(f);
  x += 0x7fff + ((x >> 16) & 1);
  return (u16)(x >> 16);
}
__device__ __forceinline__ unsigned int pk2bf(float lo, float hi) {
  return ((__float_as_uint(lo) + 0x8000u) >> 16) | ((__float_as_uint(hi) + 0x8000u) & 0xffff0000u);
}

// K=16 bf16 MFMA: B-operand k-layout (k=quad*4+j) matches the C-layout of a
// prior MFMA (rows quad*4+r) -> P^T feeds PV directly from registers.
__device__ __forceinline__ f32x4 mfma16(s16x4 a, s16x4 b, f32x4 c) {
#if __has_builtin(__builtin_amdgcn_mfma_f32_16x16x16_bf16)
  return __builtin_amdgcn_mfma_f32_16x16x16_bf16(a, b, c, 0, 0, 0);
#else
  return __builtin_amdgcn_mfma_f32_16x16x16bf16_1k(a, b, c, 0, 0, 0);
#endif
}

// ---------------- prep: 6 weight transposes + 2 activation cvts (one dispatch)
__global__ void prep8_k(
    const float* __restrict__ Wq, const float* __restrict__ Wk,
    const float* __restrict__ Wv, const float* __restrict__ Wo,
    const float* __restrict__ W1, const float* __restrict__ W2,
    const float* __restrict__ x, const float* __restrict__ y,
    u16* __restrict__ WqT, u16* __restrict__ WkT, u16* __restrict__ WvT,
    u16* __restrict__ WoT, u16* __restrict__ W1T, u16* __restrict__ W2T,
    u16* __restrict__ xb, u16* __restrict__ yb) {
  __shared__ u16 tile[32][33];
  const int z = blockIdx.z;
  const int tx = threadIdx.x, ty = threadIdx.y;
  if (z >= 6) {
    const float* in = (z == 7) ? y : x;
    u16* outp = (z == 7) ? yb : xb;
    const int tid = ty * 32 + tx;
    const long i = ((long)blockIdx.y * 128 + blockIdx.x) * 256 + tid;
    float4 v = ((const float4*)in)[i];
    unsigned int lo = (unsigned int)f2bf(v.x) | ((unsigned int)f2bf(v.y) << 16);
    unsigned int hi = (unsigned int)f2bf(v.z) | ((unsigned int)f2bf(v.w) << 16);
    ((uint2*)outp)[i] = make_uint2(lo, hi);
    return;
  }
  const float* in; u16* outp; int R, C;
  switch (z) {
    case 0: in = Wq; outp = WqT; R = 1024; C = 1024; break;
    case 1: in = Wk; outp = WkT; R = 1024; C = 1024; break;
    case 2: in = Wv; outp = WvT; R = 1024; C = 1024; break;
    case 3: in = Wo; outp = WoT; R = 1024; C = 1024; break;
    case 4: in = W1; outp = W1T; R = 1024; C = 4096; break;
    default: in = W2; outp = W2T; R = 4096; C = 1024; break;
  }
  int c0, r0;
  if (z == 5) { c0 = blockIdx.y * 32; r0 = blockIdx.x * 32; }
  else        { c0 = blockIdx.x * 32; r0 = blockIdx.y * 32; }
  if (c0 >= C || r0 >= R) return;
  for (int i = ty; i < 32; i += 8)
    tile[i][tx] = f2bf(in[(long)(r0 + i) * C + c0 + tx]);
  __syncthreads();
  for (int i = ty; i < 32; i += 8)
    outp[(long)(c0 + i) * R + r0 + tx] = tile[tx][i];
}

// ---------------- generic bf16 GEMM: C[M,N] = A[M,K] @ Bt[N,K]^T ----------------
// m97 structure, high-TLP: best for skinny-N shapes (many small blocks).
template<int MT, int NT, int OUTF32>
__global__ __launch_bounds__(256) void gemm_bt(
    const u16* __restrict__ A, const u16* __restrict__ Bt,
    const float* __restrict__ bias, void* __restrict__ Cv,
    int K, int lda, int ldb, int ldc,
    long sA, long sB, long sC, int relu) {
  constexpr int BM = MT * 32;
  constexpr int BN = NT * 32;
  __shared__ __align__(16) u16 As[BM * 32];
  __shared__ __align__(16) u16 Bs[BN * 32];
  const int z = blockIdx.z;
  A  += (long)z * sA;
  Bt += (long)z * sB;
  const int tid  = threadIdx.x;
  const int lane = tid & 63, wave = tid >> 6;
  const int quad = lane >> 4, l15 = lane & 15;
  const int wm = wave >> 1, wn = wave & 1;
  const u16* Ab = A  + (long)(blockIdx.y * BM) * lda;
  const u16* Bb = Bt + (long)(blockIdx.x * BN) * ldb;

  f32x4 acc[MT][NT];
#pragma unroll
  for (int i = 0; i < MT; ++i)
#pragma unroll
    for (int j = 0; j < NT; ++j) acc[i][j] = (f32x4){0.f, 0.f, 0.f, 0.f};

  const int r0  = tid >> 2;
  const int kk0 = (tid & 3) * 8;

  for (int kt = 0; kt < K; kt += 32) {
#pragma unroll
    for (int p = 0; p < BM / 64; ++p) {
      __builtin_amdgcn_global_load_lds(
          (const __attribute__((address_space(1))) void*)(Ab + (long)(p * 64 + r0) * lda + kt + kk0),
          (__attribute__((address_space(3))) void*)(&As[p * 2048 + tid * 8]), 16, 0, 0);
    }
#pragma unroll
    for (int p = 0; p < BN / 64; ++p) {
      __builtin_amdgcn_global_load_lds(
          (const __attribute__((address_space(1))) void*)(Bb + (long)(p * 64 + r0) * ldb + kt + kk0),
          (__attribute__((address_space(3))) void*)(&Bs[p * 2048 + tid * 8]), 16, 0, 0);
    }
    __syncthreads();
    short8 af[MT], bfr[NT];
#pragma unroll
    for (int mt = 0; mt < MT; ++mt)
      af[mt] = *(const short8*)&As[(wm * (MT * 16) + mt * 16 + l15) * 32 + quad * 8];
#pragma unroll
    for (int nt = 0; nt < NT; ++nt)
      bfr[nt] = *(const short8*)&Bs[(wn * (NT * 16) + nt * 16 + l15) * 32 + quad * 8];
#pragma unroll
    for (int mt = 0; mt < MT; ++mt)
#pragma unroll
      for (int nt = 0; nt < NT; ++nt)
        acc[mt][nt] = __builtin_amdgcn_mfma_f32_16x16x32_bf16(af[mt], bfr[nt], acc[mt][nt], 0, 0, 0);
    __syncthreads();
  }

#pragma unroll
  for (int nt = 0; nt < NT; ++nt) {
    const int col = blockIdx.x * BN + wn * (NT * 16) + nt * 16 + l15;
    const float bvv = bias ? bias[col] : 0.f;
#pragma unroll
    for (int mt = 0; mt < MT; ++mt) {
#pragma unroll
      for (int r = 0; r < 4; ++r) {
        const int row = blockIdx.y * BM + wm * (MT * 16) + mt * 16 + quad * 4 + r;
        float v = acc[mt][nt][r] + bvv;
        if (relu) v = fmaxf(v, 0.f);
        if (OUTF32) ((float*)Cv)[(long)z * sC + (long)row * ldc + col] = v;
        else        ((u16*)Cv)[(long)z * sC + (long)row * ldc + col] = f2bf(v);
      }
    }
  }
}

// ---------------- 256x256 pipelined bf16 GEMM (T2+T3+T4+T5) --------------------
template<int RELU>
__global__ __launch_bounds__(512, 2) void gemm256_k(
    const u16* __restrict__ A, const u16* __restrict__ Bt,
    const float* __restrict__ bias, u16* __restrict__ C,
    int K, int lda, int ldb, int ldc, int kOff, long sC) {
  __shared__ __align__(16) u16 lds[65536];  // A slots [0,32768) u16, B slots [32768,65536)
  const int bx = blockIdx.x, by = blockIdx.y, z = blockIdx.z;
  A  += (long)z * kOff;
  Bt += (long)z * kOff;
  const int tid = threadIdx.x;
  const int lane = tid & 63, w = tid >> 6;
  const int quad = lane >> 4, l15 = lane & 15;
  const int wm = w >> 2, wn = w & 3;

  const int srow = w * 16 + l15;
  const u16* a0p = A + (long)(by * 256 + srow) * lda + quad * 8;
  const u16* a1p = a0p + (long)128 * lda;
  const u16* b0p = Bt + (long)(bx * 256 + srow) * ldb + quad * 8;
  const u16* b1p = b0p + (long)128 * ldb;

  f32x4 acc[8][4];
#pragma unroll
  for (int i = 0; i < 8; ++i)
#pragma unroll
    for (int j = 0; j < 4; ++j) acc[i][j] = (f32x4){0.f, 0.f, 0.f, 0.f};

  auto STAGE = [&](int c) {
    const int sl = (c & 3) * 8192;
    const long ko = (long)c * 32;
    __builtin_amdgcn_global_load_lds(
        (const __attribute__((address_space(1))) void*)(a0p + ko),
        (__attribute__((address_space(3))) void*)(&lds[sl + tid * 8]), 16, 0, 0);
    __builtin_amdgcn_global_load_lds(
        (const __attribute__((address_space(1))) void*)(a1p + ko),
        (__attribute__((address_space(3))) void*)(&lds[sl + 4096 + tid * 8]), 16, 0, 0);
    __builtin_amdgcn_global_load_lds(
        (const __attribute__((address_space(1))) void*)(b0p + ko),
        (__attribute__((address_space(3))) void*)(&lds[32768 + sl + tid * 8]), 16, 0, 0);
    __builtin_amdgcn_global_load_lds(
        (const __attribute__((address_space(1))) void*)(b1p + ko),
        (__attribute__((address_space(3))) void*)(&lds[32768 + sl + 4096 + tid * 8]), 16, 0, 0);
  };

  auto COMPUTE = [&](int t) {
    const int sl = (t & 3) * 8192;
    short8 af[8], bfv[4];
#pragma unroll
    for (int fr = 0; fr < 8; ++fr)
      af[fr] = *(const short8*)&lds[sl + ((wm * 8 + fr) * 64 + lane) * 8];
#pragma unroll
    for (int fc = 0; fc < 4; ++fc)
      bfv[fc] = *(const short8*)&lds[32768 + sl + ((wn * 4 + fc) * 64 + lane) * 8];
    __builtin_amdgcn_s_setprio(1);
#pragma unroll
    for (int fr = 0; fr < 8; ++fr)
#pragma unroll
      for (int fc = 0; fc < 4; ++fc)
        acc[fr][fc] = __builtin_amdgcn_mfma_f32_16x16x32_bf16(af[fr], bfv[fc], acc[fr][fc], 0, 0, 0);
    __builtin_amdgcn_s_setprio(0);
  };

  const int NT = K >> 5;  // requires NT >= 3
  STAGE(0); STAGE(1); STAGE(2);
  for (int t = 0; t < NT - 2; ++t) {
    asm volatile("s_waitcnt vmcnt(8)" ::: "memory");
    __builtin_amdgcn_s_barrier();
    __builtin_amdgcn_sched_barrier(0);
    if (t + 3 < NT) STAGE(t + 3);
    COMPUTE(t);
  }
  asm volatile("s_waitcnt vmcnt(4)" ::: "memory");
  __builtin_amdgcn_s_barrier();
  __builtin_amdgcn_sched_barrier(0);
  COMPUTE(NT - 2);
  asm volatile("s_waitcnt vmcnt(0)" ::: "memory");
  __builtin_amdgcn_s_barrier();
  __builtin_amdgcn_sched_barrier(0);
  COMPUTE(NT - 1);

  C += (long)z * sC;
#pragma unroll
  for (int fc = 0; fc < 4; ++fc) {
    const int col = bx * 256 + wn * 64 + fc * 16 + l15;
    const float bvv = bias ? bias[col] : 0.f;
#pragma unroll
    for (int fr = 0; fr < 8; ++fr) {
      const long row = by * 256 + wm * 128 + fr * 16 + quad * 4;
#pragma unroll
      for (int r = 0; r < 4; ++r) {
        float v = acc[fr][fc][r] + bvv;
        if (RELU) v = fmaxf(v, 0.f);
        C[(row + r) * ldc + col] = f2bf(v);
      }
    }
  }
}

// ---------------- QKV batched GEMM (m97 structure; V written TRANSPOSED) ------
// z=0: Q (pre-scaled), z=1: K, z=2: V -> Vt[bh][d][s] via LDS transpose tile
// (vtrans fused; saves a dispatch + 16MB Vp round-trip).
__global__ __launch_bounds__(256) void qkv_k(
    const u16* __restrict__ xb, const u16* __restrict__ yb,
    const u16* __restrict__ WqT, const u16* __restrict__ WkT, const u16* __restrict__ WvT,
    const float* __restrict__ bq, const float* __restrict__ bk, const float* __restrict__ bv,
    u16* __restrict__ Q, u16* __restrict__ Kp, u16* __restrict__ Vt) {
  __shared__ __align__(16) u16 As[128 * 32];
  __shared__ __align__(16) u16 Bs[128 * 32];
  __shared__ __align__(16) u16 vt[64 * 136];   // pad 136: 16B-aligned rows, 4-way banks
  const int z = blockIdx.z;
  const u16* A  = (z == 0) ? xb : yb;
  const u16* Bt = (z == 0) ? WqT : (z == 1) ? WkT : WvT;
  const float* bias = (z == 0) ? bq : (z == 1) ? bk : bv;
  const float sc = (z == 0) ? 0.18033688011112042f : 1.0f;  // 0.125*log2(e)
  const int tid  = threadIdx.x;
  const int lane = tid & 63, wave = tid >> 6;
  const int quad = lane >> 4, l15 = lane & 15;
  const int wm = wave >> 1, wn = wave & 1;
  const u16* Ab = A  + (long)(blockIdx.y * 128) * D_;
  const u16* Bb = Bt + (long)(blockIdx.x * 128) * D_;

  f32x4 acc[4][4];
#pragma unroll
  for (int i = 0; i < 4; ++i)
#pragma unroll
    for (int j = 0; j < 4; ++j) acc[i][j] = (f32x4){0.f, 0.f, 0.f, 0.f};

  const int r0  = tid >> 2;
  const int kk0 = (tid & 3) * 8;

  for (int kt = 0; kt < D_; kt += 32) {
#pragma unroll
    for (int p = 0; p < 2; ++p) {
      __builtin_amdgcn_global_load_lds(
          (const __attribute__((address_space(1))) void*)(Ab + (long)(p * 64 + r0) * D_ + kt + kk0),
          (__attribute__((address_space(3))) void*)(&As[p * 2048 + tid * 8]), 16, 0, 0);
      __builtin_amdgcn_global_load_lds(
          (const __attribute__((address_space(1))) void*)(Bb + (long)(p * 64 + r0) * D_ + kt + kk0),
          (__attribute__((address_space(3))) void*)(&Bs[p * 2048 + tid * 8]), 16, 0, 0);
    }
    __syncthreads();
    short8 af[4], bfr[4];
#pragma unroll
    for (int mt = 0; mt < 4; ++mt)
      af[mt] = *(const short8*)&As[(wm * 64 + mt * 16 + l15) * 32 + quad * 8];
#pragma unroll
    for (int nt = 0; nt < 4; ++nt)
      bfr[nt] = *(const short8*)&Bs[(wn * 64 + nt * 16 + l15) * 32 + quad * 8];
#pragma unroll
    for (int mt = 0; mt < 4; ++mt)
#pragma unroll
      for (int nt = 0; nt < 4; ++nt)
        acc[mt][nt] = __builtin_amdgcn_mfma_f32_16x16x32_bf16(af[mt], bfr[nt], acc[mt][nt], 0, 0, 0);
    __syncthreads();
  }

  if (z != 2) {
    u16* C = (z == 0) ? Q : Kp;
#pragma unroll
    for (int nt = 0; nt < 4; ++nt) {
      const int col = blockIdx.x * 128 + wn * 64 + nt * 16 + l15;
      const float bvv = bias[col];
#pragma unroll
      for (int mt = 0; mt < 4; ++mt) {
#pragma unroll
        for (int r = 0; r < 4; ++r) {
          const int row = blockIdx.y * 128 + wm * 64 + mt * 16 + quad * 4 + r;
          C[(long)row * D_ + col] = f2bf((acc[mt][nt][r] + bvv) * sc);
        }
      }
    }
  } else {
    // V: write transposed. Block tile = rows [by*128,+128) x cols [bx*128,+128)
    // = 2 heads (hh=0,1 <-> wn). Two passes through the 64x128 LDS tile.
    const int brow = blockIdx.y * 128;
    const int b = brow >> 11;
#pragma unroll
    for (int hh = 0; hh < 2; ++hh) {
      if (wn == hh) {
#pragma unroll
        for (int nt = 0; nt < 4; ++nt) {
          const int dl = nt * 16 + l15;                       // d in [0,64)
          const float bvv = bias[blockIdx.x * 128 + hh * 64 + dl];
#pragma unroll
          for (int mt = 0; mt < 4; ++mt) {
#pragma unroll
            for (int r = 0; r < 4; ++r)
              vt[dl * 136 + wm * 64 + mt * 16 + quad * 4 + r] = f2bf(acc[mt][nt][r] + bvv);
          }
        }
      }
      __syncthreads();
      // store: 256 threads; thread -> d = tid>>2, s chunk = (tid&3)*32
      const int d = tid >> 2, sl = (tid & 3) * 32;
      const int h = blockIdx.x * 2 + hh;
      u16* dst = Vt + ((long)(b * 16 + h) * DK_ + d) * S_ + (brow & 2047) + sl;
#pragma unroll
      for (int c = 0; c < 4; ++c)
        *(uint4*)(dst + c * 8) = *(const uint4*)&vt[d * 136 + sl + c * 8];
      if (hh == 0) __syncthreads();
    }
  }
}

// ---------------- fused flash attention v8: QBLK=256 + T15 QK-ahead pipeline --
// grid (B*H=32, S/256=8) = 256 blocks (1/CU), 512 thr (8 waves). Wave w owns
// q rows [w*32,+32). Per tile t: stage(t+1) -> barrier -> QK(t+1) overlaps
// SM(t)+PV(t) (MFMA pipe || VALU/trans pipe; chain shortened by the QK leg).
// P stays in registers via the transposed-QK^T / K=16-MFMA pairing.
__global__ __launch_bounds__(512, 2) void flash_k(
    const u16* __restrict__ Q, const u16* __restrict__ Kp, const u16* __restrict__ Vt,
    const int* __restrict__ mask, u16* __restrict__ ctx) {
  __shared__ __align__(16) u16 sQ[16384];      // 32KB: 32 panels
  __shared__ __align__(16) u16 sK[2][2048];    // 8KB: 2 buf x 4 panels [mk*2+kt]
  __shared__ __align__(16) u16 sV[2][2048];    // 8KB: 2 buf x 256 slots x 16B
  __shared__ int s_allones;

  const int bh = blockIdx.x, qt = blockIdx.y;
  const int b = bh >> 4, h = bh & 15;
  const int tid = threadIdx.x;
  const int w = tid >> 6, lane = tid & 63;
  const int quad = lane >> 4, l15 = lane & 15;

  const u16* Qg  = Q  + ((long)b * S_ + qt * 256) * D_ + h * DK_;
  const u16* Kg  = Kp + (long)b * S_ * D_ + h * DK_;
  const u16* Vtg = Vt + (long)bh * DK_ * S_;
  const int* maskg = mask + (long)b * S_;
  u16* ctxg = ctx + ((long)b * S_ + qt * 256) * D_ + h * DK_;

  // staging: waves 0-3 stage K; waves 4-7 stage V (one 16B slot each/tile)
  const int isK = tid < 256;
  const int t2 = tid & 255;
  const int krow = t2 >> 3, kc = t2 & 7;           // K: 32 kv-rows x 8 d-chunks
  const int vd  = ((t2 >> 6) << 4) | (t2 & 15);    // V: slot t2
  const int vq4 = ((t2 >> 4) & 3) * 4;
  const u16* gptr = isK ? (Kg + (long)krow * D_ + kc * 8)
                        : (Vtg + (long)vd * S_ + vq4);
  const long gstep = isK ? (long)32 * D_ : (long)32;
  const int ksw = (((krow >> 4) * 2 + (kc >> 2)) * 64 + SLOT(kc & 3, krow & 15)) * 8;
  u16* sdst0 = isK ? &sK[0][ksw] : &sV[0][t2 * 8];
  u16* sdst1 = isK ? &sK[1][ksw] : &sV[1][t2 * 8];

  auto gload = [&](const u16* p) {
    uint4 r;
    if (isK) {
      r = *(const uint4*)p;
    } else {
      uint2 lo = *(const uint2*)p;
      uint2 hi = *(const uint2*)(p + 16);
      r = make_uint4(lo.x, lo.y, hi.x, hi.y);
    }
    return r;
  };

  uint4 reg = gload(gptr);

  // mask all-ones check (block-uniform fast path; masked path kept below)
  int part = 1;
  for (int i = tid; i < S_; i += 512) part &= (maskg[i] != 0);
  if (tid == 0) s_allones = 1;

  // stage Q: 256 rows x 64 cols, frag-linear (4 x uint4 per thread)
#pragma unroll
  for (int p = 0; p < 4; ++p) {
    const int idx = p * 512 + tid;
    const int row = idx >> 3, cb = idx & 7;
    uint4 v = *(const uint4*)(Qg + (long)row * D_ + cb * 8);
    *(uint4*)&sQ[(((row >> 4) * 2 + (cb >> 2)) * 64 + SLOT(cb & 3, row & 15)) * 8] = v;
  }
  *(uint4*)sdst0 = reg;
  reg = gload(gptr + gstep);
  gptr += 2 * gstep;
  __syncthreads();

  const int rslot = SLOT(quad, l15) * 8;   // reader offset within a K/Q panel

  short8 qf[2][2];
#pragma unroll
  for (int mf = 0; mf < 2; ++mf)
#pragma unroll
    for (int kt = 0; kt < 2; ++kt)
      qf[mf][kt] = *(const short8*)&sQ[(((w * 2 + mf) * 2 + kt) * 64) * 8 + rslot];

  // QK(0) -> sc (tile 0 is in sK[0])
  f32x4 sc_[2][2], sn_[2][2];
#pragma unroll
  for (int i = 0; i < 2; ++i)
#pragma unroll
    for (int j = 0; j < 2; ++j) sc_[i][j] = (f32x4){0.f, 0.f, 0.f, 0.f};
#pragma unroll
  for (int kt = 0; kt < 2; ++kt) {
    short8 kf0 = *(const short8*)&sK[0][(kt * 64) * 8 + rslot];
    short8 kf1 = *(const short8*)&sK[0][((2 + kt) * 64) * 8 + rslot];
#pragma unroll
    for (int mf = 0; mf < 2; ++mf) {
      sc_[0][mf] = __builtin_amdgcn_mfma_f32_16x16x32_bf16(kf0, qf[mf][kt], sc_[0][mf], 0, 0, 0);
      sc_[1][mf] = __builtin_amdgcn_mfma_f32_16x16x32_bf16(kf1, qf[mf][kt], sc_[1][mf], 0, 0, 0);
    }
  }

  if (!part) s_allones = 0;
  __syncthreads();
  const int allones = s_allones;

  float lsum[2] = {0.f, 0.f};
  f32x4 accOT[2][4];   // O^T: [mf][n], col q=l15, rows d = n*16 + quad*4 + r
#pragma unroll
  for (int i = 0; i < 2; ++i)
#pragma unroll
    for (int j = 0; j < 4; ++j) accOT[i][j] = (f32x4){0.f, 0.f, 0.f, 0.f};

  for (int t = 0; t < 64; ++t) {
    if (t) __syncthreads();                      // A: prior reads of buf (t+1)&1 done
    const int buf = t & 1;
    if (t < 63) {
      *(uint4*)((t & 1) ? sdst0 : sdst1) = reg;  // stage tile t+1 -> buf (t+1)&1
      if (t < 62) {
        reg = gload(gptr);
        gptr += gstep;
      }
      __syncthreads();                           // B: tile t+1 visible
      // QK(t+1) -> sn  (overlaps SM(t)+PV(t) below)
      const int nb = buf ^ 1;
#pragma unroll
      for (int i = 0; i < 2; ++i)
#pragma unroll
        for (int j = 0; j < 2; ++j) sn_[i][j] = (f32x4){0.f, 0.f, 0.f, 0.f};
#pragma unroll
      for (int kt = 0; kt < 2; ++kt) {
        short8 kf0 = *(const short8*)&sK[nb][(kt * 64) * 8 + rslot];
        short8 kf1 = *(const short8*)&sK[nb][((2 + kt) * 64) * 8 + rslot];
#pragma unroll
        for (int mf = 0; mf < 2; ++mf) {
          sn_[0][mf] = __builtin_amdgcn_mfma_f32_16x16x32_bf16(kf0, qf[mf][kt], sn_[0][mf], 0, 0, 0);
          sn_[1][mf] = __builtin_amdgcn_mfma_f32_16x16x32_bf16(kf1, qf[mf][kt], sn_[1][mf], 0, 0, 0);
        }
      }
    }
    // softmax numerator -> P^T bf16, in registers (k=quad*4+r layout)
    s16x4 pb[2][2];
    if (allones) {
#pragma unroll
      for (int mk = 0; mk < 2; ++mk)
#pragma unroll
        for (int mf = 0; mf < 2; ++mf) {
          float p0 = __builtin_amdgcn_exp2f(sc_[mk][mf][0]);
          float p1 = __builtin_amdgcn_exp2f(sc_[mk][mf][1]);
          float p2 = __builtin_amdgcn_exp2f(sc_[mk][mf][2]);
          float p3 = __builtin_amdgcn_exp2f(sc_[mk][mf][3]);
          lsum[mf] += (p0 + p1) + (p2 + p3);
          *(uint2*)&pb[mk][mf] = make_uint2(pk2bf(p0, p1), pk2bf(p2, p3));
        }
    } else {
      const int4 mv0 = *(const int4*)(maskg + t * 32 + quad * 4);
      const int4 mv1 = *(const int4*)(maskg + t * 32 + 16 + quad * 4);
#pragma unroll
      for (int mk = 0; mk < 2; ++mk) {
        const int4 mv = mk ? mv1 : mv0;
#pragma unroll
        for (int mf = 0; mf < 2; ++mf) {
          float p0 = mv.x ? __builtin_amdgcn_exp2f(sc_[mk][mf][0]) : 0.f;
          float p1 = mv.y ? __builtin_amdgcn_exp2f(sc_[mk][mf][1]) : 0.f;
          float p2 = mv.z ? __builtin_amdgcn_exp2f(sc_[mk][mf][2]) : 0.f;
          float p3 = mv.w ? __builtin_amdgcn_exp2f(sc_[mk][mf][3]) : 0.f;
          lsum[mf] += (p0 + p1) + (p2 + p3);
          *(uint2*)&pb[mk][mf] = make_uint2(pk2bf(p0, p1), pk2bf(p2, p3));
        }
      }
    }
    // PV: O^T[d 64][q 32] += V^T @ P^T via K=16 MFMA (reads sV[buf] = tile t)
#pragma unroll
    for (int n = 0; n < 4; ++n) {
      short8 vv = *(const short8*)&sV[buf][(n * 64 + lane) * 8];
      s16x4 v0 = __builtin_shufflevector(vv, vv, 0, 1, 2, 3);
      s16x4 v1 = __builtin_shufflevector(vv, vv, 4, 5, 6, 7);
#pragma unroll
      for (int mf = 0; mf < 2; ++mf) {
        accOT[mf][n] = mfma16(v0, pb[0][mf], accOT[mf][n]);
        accOT[mf][n] = mfma16(v1, pb[1][mf], accOT[mf][n]);
      }
    }
    // rotate: sc <- sn (static indices; compiler renames)
#pragma unroll
    for (int i = 0; i < 2; ++i)
#pragma unroll
      for (int j = 0; j < 2; ++j) sc_[i][j] = sn_[i][j];
  }

  // epilogue: lsum reduce over quads; O^T cols share q=l15 -> per-lane inv
#pragma unroll
  for (int mf = 0; mf < 2; ++mf) {
    lsum[mf] += __shfl_xor(lsum[mf], 16, 64);
    lsum[mf] += __shfl_xor(lsum[mf], 32, 64);
  }
  const float inv0 = 1.f / lsum[0], inv1 = 1.f / lsum[1];
#pragma unroll
  for (int mf = 0; mf < 2; ++mf) {
    const float iv = mf ? inv1 : inv0;
    u16* cp = ctxg + (long)(w * 32 + mf * 16 + l15) * D_;
#pragma unroll
    for (int n = 0; n < 4; ++n) {
      float o0 = accOT[mf][n][0] * iv;
      float o1 = accOT[mf][n][1] * iv;
      float o2 = accOT[mf][n][2] * iv;
      float o3 = accOT[mf][n][3] * iv;
      *(uint2*)(cp + n * 16 + quad * 4) = make_uint2(pk2bf(o0, o1), pk2bf(o2, o3));
    }
  }
}

// ---------------- add + layernorm helpers ----------------
__device__ __forceinline__ float block_reduce_sum(float v, float* red) {
#pragma unroll
  for (int off = 32; off; off >>= 1) v += __shfl_down(v, off, 64);
  __syncthreads();
  if ((threadIdx.x & 63) == 0) red[threadIdx.x >> 6] = v;
  __syncthreads();
  return red[0] + red[1] + red[2] + red[3];
}

// x (fp32) + mha0 + mha1 (bf16 split-K partials) + bo -> LN -> x1 (bf16)
__global__ __launch_bounds__(256) void addln_fb(const float* __restrict__ A,
    const u16* __restrict__ M0, const u16* __restrict__ M1, const float* __restrict__ bo,
    const float* __restrict__ g, const float* __restrict__ be, u16* __restrict__ outp) {
  __shared__ float red[4];
  const int row = blockIdx.x, tid = threadIdx.x;
  const float4 av = ((const float4*)(A + (long)row * D_))[tid];
  const uint2 m0 = ((const uint2*)(M0 + (long)row * D_))[tid];
  const uint2 m1 = ((const uint2*)(M1 + (long)row * D_))[tid];
  const int c0 = tid * 4;
  float xv[4];
  xv[0] = av.x + bf2f((u16)(m0.x & 0xffff)) + bf2f((u16)(m1.x & 0xffff)) + bo[c0 + 0];
  xv[1] = av.y + bf2f((u16)(m0.x >> 16))    + bf2f((u16)(m1.x >> 16))    + bo[c0 + 1];
  xv[2] = av.z + bf2f((u16)(m0.y & 0xffff)) + bf2f((u16)(m1.y & 0xffff)) + bo[c0 + 2];
  xv[3] = av.w + bf2f((u16)(m0.y >> 16))    + bf2f((u16)(m1.y >> 16))    + bo[c0 + 3];
  float s  = xv[0] + xv[1] + xv[2] + xv[3];
  float ss = xv[0]*xv[0] + xv[1]*xv[1] + xv[2]*xv[2] + xv[3]*xv[3];
  s  = block_reduce_sum(s, red);
  ss = block_reduce_sum(ss, red);
  const float m   = s * (1.0f / 1024.0f);
  const float var = ss * (1.0f / 1024.0f) - m * m;
  const float rs  = rsqrtf(var + 1e-5f);
  float v0 = (xv[0] - m) * rs * g[c0 + 0] + be[c0 + 0];
  float v1 = (xv[1] - m) * rs * g[c0 + 1] + be[c0 + 1];
  float v2 = (xv[2] - m) * rs * g[c0 + 2] + be[c0 + 2];
  float v3 = (xv[3] - m) * rs * g[c0 + 3] + be[c0 + 3];
  unsigned int o01 = (unsigned int)f2bf(v0) | ((unsigned int)f2bf(v1) << 16);
  unsigned int o23 = (unsigned int)f2bf(v2) | ((unsigned int)f2bf(v3) << 16);
  ((uint2*)(outp + (long)row * D_))[tid] = make_uint2(o01, o23);
}

// x1 (bf16) + ff0..ff3 (bf16 split-K partials) + b2 -> LN -> out (fp32)
__global__ __launch_bounds__(256) void addln2_bf(const u16* __restrict__ A,
    const u16* __restrict__ F0, const u16* __restrict__ F1,
    const u16* __restrict__ F2, const u16* __restrict__ F3,
    const float* __restrict__ b2,
    const float* __restrict__ g, const float* __restrict__ be, float* __restrict__ outp) {
  __shared__ float red[4];
  const int row = blockIdx.x, tid = threadIdx.x;
  const uint2 av = ((const uint2*)(A + (long)row * D_))[tid];
  const uint2 f0 = ((const uint2*)(F0 + (long)row * D_))[tid];
  const uint2 f1 = ((const uint2*)(F1 + (long)row * D_))[tid];
  const uint2 f2 = ((const uint2*)(F2 + (long)row * D_))[tid];
  const uint2 f3 = ((const uint2*)(F3 + (long)row * D_))[tid];
  const int c0 = tid * 4;
  float xv[4];
  xv[0] = bf2f((u16)(av.x & 0xffff)) + bf2f((u16)(f0.x & 0xffff)) + bf2f((u16)(f1.x & 0xffff))
        + bf2f((u16)(f2.x & 0xffff)) + bf2f((u16)(f3.x & 0xffff)) + b2[c0 + 0];
  xv[1] = bf2f((u16)(av.x >> 16))    + bf2f((u16)(f0.x >> 16))    + bf2f((u16)(f1.x >> 16))
        + bf2f((u16)(f2.x >> 16))    + bf2f((u16)(f3.x >> 16))    + b2[c0 + 1];
  xv[2] = bf2f((u16)(av.y & 0xffff)) + bf2f((u16)(f0.y & 0xffff)) + bf2f((u16)(f1.y & 0xffff))
        + bf2f((u16)(f2.y & 0xffff)) + bf2f((u16)(f3.y & 0xffff)) + b2[c0 + 2];
  xv[3] = bf2f((u16)(av.y >> 16))    + bf2f((u16)(f0.y >> 16))    + bf2f((u16)(f1.y >> 16))
        + bf2f((u16)(f2.y >> 16))    + bf2f((u16)(f3.y >> 16))    + b2[c0 + 3];
  float s  = xv[0] + xv[1] + xv[2] + xv[3];
  float ss = xv[0]*xv[0] + xv[1]*xv[1] + xv[2]*xv[2] + xv[3]*xv[3];
  s  = block_reduce_sum(s, red);
  ss = block_reduce_sum(ss, red);
  const float m   = s * (1.0f / 1024.0f);
  const float var = ss * (1.0f / 1024.0f) - m * m;
  const float rs  = rsqrtf(var + 1e-5f);
  float4 o;
  o.x = (xv[0] - m) * rs * g[c0 + 0] + be[c0 + 0];
  o.y = (xv[1] - m) * rs * g[c0 + 1] + be[c0 + 1];
  o.z = (xv[2] - m) * rs * g[c0 + 2] + be[c0 + 2];
  o.w = (xv[3] - m) * rs * g[c0 + 3] + be[c0 + 3];
  ((float4*)(outp + (long)row * D_))[tid] = o;
}

extern "C" void kernel_launch(void* const* d_in, const int* in_sizes, int n_in,
                              void* d_out, int out_size, void* d_ws, size_t ws_size,
                              hipStream_t stream) {
  const float* x   = (const float*)d_in[0];
  const float* y   = (const float*)d_in[1];
  const int* mask  = (const int*)d_in[2];
  const float* Wq = (const float*)d_in[3];  const float* bq = (const float*)d_in[4];
  const float* Wk = (const float*)d_in[5];  const float* bk = (const float*)d_in[6];
  const float* Wv = (const float*)d_in[7];  const float* bv = (const float*)d_in[8];
  const float* Wo = (const float*)d_in[9];  const float* bo = (const float*)d_in[10];
  const float* W1 = (const float*)d_in[11]; const float* b1 = (const float*)d_in[12];
  const float* W2 = (const float*)d_in[13]; const float* b2 = (const float*)d_in[14];
  const float* g1 = (const float*)d_in[15]; const float* be1 = (const float*)d_in[16];
  const float* g2 = (const float*)d_in[17]; const float* be2 = (const float*)d_in[18];
  float* out = (float*)d_out;

  char* w = (char*)d_ws;
  const size_t MB = 1024 * 1024;
  u16* WqT = (u16*)(w + 0 * MB);
  u16* WkT = (u16*)(w + 2 * MB);
  u16* WvT = (u16*)(w + 4 * MB);
  u16* WoT = (u16*)(w + 6 * MB);
  u16* W1T = (u16*)(w + 8 * MB);     // 8MB  [HID][D]
  u16* W2T = (u16*)(w + 16 * MB);    // 8MB  [D][HID]
  u16* xb  = (u16*)(w + 24 * MB);    // dead after qkv; x1 reuses
  u16* yb  = (u16*)(w + 32 * MB);    // dead after qkv
  u16* Q   = (u16*)(w + 40 * MB);    // dead after flash; ff partials reuse
  u16* Kp  = (u16*)(w + 48 * MB);    // dead after flash
  u16* Vt  = (u16*)(w + 64 * MB);    // dead after flash (written by qkv z=2)
  u16* ctx = (u16*)(w + 72 * MB);    // dead after Wo gemm
  u16* mha = (u16*)(w + 80 * MB);    // 2 x 8MB bf16 split-K partials (80..96)
  u16* x1  = (u16*)(w + 24 * MB);    // reuses xb; live through addln2
  u16* h1  = (u16*)(w + 96 * MB);    // 32MB bf16 [4096][4096]
  u16* ff  = (u16*)(w + 40 * MB);    // 4 x 8MB bf16 split-K partials (40..72)

  // prep: 6 weight transposes + 2 activation cvts, ONE dispatch
  prep8_k<<<dim3(128, 32, 8), dim3(32, 8), 0, stream>>>(Wq, Wk, Wv, Wo, W1, W2,
      x, y, WqT, WkT, WvT, WoT, W1T, W2T, xb, yb);

  // QKV: m97 structure, 768 blocks; V written transposed (vtrans fused)
  qkv_k<<<dim3(8, 32, 3), 256, 0, stream>>>(xb, yb, WqT, WkT, WvT, bq, bk, bv, Q, Kp, Vt);

  // fused flash attention v8: QBLK=256 + T15 QK-ahead pipeline, 256 blocks
  flash_k<<<dim3(32, 8), 512, 0, stream>>>(Q, Kp, Vt, mask, ctx);

  // output projection: split-K=2 on gemm_bt (512 blocks); bo folded into LN1
  gemm_bt<4, 4, 0><<<dim3(8, 32, 2), 256, 0, stream>>>(ctx, WoT, nullptr, mha,
      512, 1024, 1024, 1024, 512, 512, (long)4096 * 1024, 0);
  addln_fb<<<dim3(4096), 256, 0, stream>>>(x, mha, mha + (long)4096 * 1024, bo, g1, be1, x1);

  // FFN1: 256 blocks, pipelined 256x256 kernel
  gemm256_k<1><<<dim3(16, 16, 1), 512, 0, stream>>>(x1, W1T, b1, h1,
      1024, 1024, 1024, 4096, 0, 0);
  // FFN2: split-K=4, bf16 partials (256 blocks); b2 folded into LN2
  gemm256_k<0><<<dim3(4, 16, 4), 512, 0, stream>>>(h1, W2T, nullptr, ff,
      1024, 4096, 4096, 1024, 1024, (long)4096 * 1024);
  addln2_bf<<<dim3(4096), 256, 0, stream>>>(x1, ff, ff + (long)4096 * 1024,
      ff + (long)2 * 4096 * 1024, ff + (long)3 * 4096 * 1024, b2, g2, be2, out);
}

// Round 7
// 390.178 us; speedup vs baseline: 1.0405x; 1.0405x over previous
//
#include <hip/hip_runtime.h>

#define S_ 2048
#define D_ 1024
#define B_ 2
#define H_ 16
#define DK_ 64
#define HID_ 4096

typedef unsigned short u16;
typedef __attribute__((ext_vector_type(8))) short short8;
typedef __attribute__((ext_vector_type(4))) short s16x4;
typedef __attribute__((ext_vector_type(4))) float f32x4;

// frag-linear slot with bank-spreading XOR: panel of 64 slots x 16B
#define SLOT(q16, r16) (((q16) * 16) + ((r16) ^ (q16)))

__device__ __forceinline__ float bf2f(u16 u) {
  return __uint_as_float(((unsigned int)u) << 16);
}
__device__ __forceinline__ u16 f2bf(float f) {
  unsigned int x = __float_as_uint(f);
  x += 0x7fff + ((x >> 16) & 1);
  return (u16)(x >> 16);
}
__device__ __forceinline__ unsigned int pk2bf(float lo, float hi) {
  return ((__float_as_uint(lo) + 0x8000u) >> 16) | ((__float_as_uint(hi) + 0x8000u) & 0xffff0000u);
}

// K=16 bf16 MFMA: B-operand k-layout (k=quad*4+j) matches the C-layout of a
// prior MFMA (rows quad*4+r) -> P^T feeds PV directly from registers.
__device__ __forceinline__ f32x4 mfma16(s16x4 a, s16x4 b, f32x4 c) {
#if __has_builtin(__builtin_amdgcn_mfma_f32_16x16x16_bf16)
  return __builtin_amdgcn_mfma_f32_16x16x16_bf16(a, b, c, 0, 0, 0);
#else
  return __builtin_amdgcn_mfma_f32_16x16x16bf16_1k(a, b, c, 0, 0, 0);
#endif
}

// ---------------- prep: 6 weight transposes + 2 activation cvts (one dispatch)
__global__ void prep8_k(
    const float* __restrict__ Wq, const float* __restrict__ Wk,
    const float* __restrict__ Wv, const float* __restrict__ Wo,
    const float* __restrict__ W1, const float* __restrict__ W2,
    const float* __restrict__ x, const float* __restrict__ y,
    u16* __restrict__ WqT, u16* __restrict__ WkT, u16* __restrict__ WvT,
    u16* __restrict__ WoT, u16* __restrict__ W1T, u16* __restrict__ W2T,
    u16* __restrict__ xb, u16* __restrict__ yb) {
  __shared__ u16 tile[32][33];
  const int z = blockIdx.z;
  const int tx = threadIdx.x, ty = threadIdx.y;
  if (z >= 6) {
    const float* in = (z == 7) ? y : x;
    u16* outp = (z == 7) ? yb : xb;
    const int tid = ty * 32 + tx;
    const long i = ((long)blockIdx.y * 128 + blockIdx.x) * 256 + tid;
    float4 v = ((const float4*)in)[i];
    unsigned int lo = (unsigned int)f2bf(v.x) | ((unsigned int)f2bf(v.y) << 16);
    unsigned int hi = (unsigned int)f2bf(v.z) | ((unsigned int)f2bf(v.w) << 16);
    ((uint2*)outp)[i] = make_uint2(lo, hi);
    return;
  }
  const float* in; u16* outp; int R, C;
  switch (z) {
    case 0: in = Wq; outp = WqT; R = 1024; C = 1024; break;
    case 1: in = Wk; outp = WkT; R = 1024; C = 1024; break;
    case 2: in = Wv; outp = WvT; R = 1024; C = 1024; break;
    case 3: in = Wo; outp = WoT; R = 1024; C = 1024; break;
    case 4: in = W1; outp = W1T; R = 1024; C = 4096; break;
    default: in = W2; outp = W2T; R = 4096; C = 1024; break;
  }
  int c0, r0;
  if (z == 5) { c0 = blockIdx.y * 32; r0 = blockIdx.x * 32; }
  else        { c0 = blockIdx.x * 32; r0 = blockIdx.y * 32; }
  if (c0 >= C || r0 >= R) return;
  for (int i = ty; i < 32; i += 8)
    tile[i][tx] = f2bf(in[(long)(r0 + i) * C + c0 + tx]);
  __syncthreads();
  for (int i = ty; i < 32; i += 8)
    outp[(long)(c0 + i) * R + r0 + tx] = tile[tx][i];
}

// ---------------- generic bf16 GEMM: C[M,N] = A[M,K] @ Bt[N,K]^T ----------------
// m97 structure, high-TLP: best for skinny-N shapes (many small blocks).
template<int MT, int NT, int OUTF32>
__global__ __launch_bounds__(256) void gemm_bt(
    const u16* __restrict__ A, const u16* __restrict__ Bt,
    const float* __restrict__ bias, void* __restrict__ Cv,
    int K, int lda, int ldb, int ldc,
    long sA, long sB, long sC, int relu) {
  constexpr int BM = MT * 32;
  constexpr int BN = NT * 32;
  __shared__ __align__(16) u16 As[BM * 32];
  __shared__ __align__(16) u16 Bs[BN * 32];
  const int z = blockIdx.z;
  A  += (long)z * sA;
  Bt += (long)z * sB;
  const int tid  = threadIdx.x;
  const int lane = tid & 63, wave = tid >> 6;
  const int quad = lane >> 4, l15 = lane & 15;
  const int wm = wave >> 1, wn = wave & 1;
  const u16* Ab = A  + (long)(blockIdx.y * BM) * lda;
  const u16* Bb = Bt + (long)(blockIdx.x * BN) * ldb;

  f32x4 acc[MT][NT];
#pragma unroll
  for (int i = 0; i < MT; ++i)
#pragma unroll
    for (int j = 0; j < NT; ++j) acc[i][j] = (f32x4){0.f, 0.f, 0.f, 0.f};

  const int r0  = tid >> 2;
  const int kk0 = (tid & 3) * 8;

  for (int kt = 0; kt < K; kt += 32) {
#pragma unroll
    for (int p = 0; p < BM / 64; ++p) {
      __builtin_amdgcn_global_load_lds(
          (const __attribute__((address_space(1))) void*)(Ab + (long)(p * 64 + r0) * lda + kt + kk0),
          (__attribute__((address_space(3))) void*)(&As[p * 2048 + tid * 8]), 16, 0, 0);
    }
#pragma unroll
    for (int p = 0; p < BN / 64; ++p) {
      __builtin_amdgcn_global_load_lds(
          (const __attribute__((address_space(1))) void*)(Bb + (long)(p * 64 + r0) * ldb + kt + kk0),
          (__attribute__((address_space(3))) void*)(&Bs[p * 2048 + tid * 8]), 16, 0, 0);
    }
    __syncthreads();
    short8 af[MT], bfr[NT];
#pragma unroll
    for (int mt = 0; mt < MT; ++mt)
      af[mt] = *(const short8*)&As[(wm * (MT * 16) + mt * 16 + l15) * 32 + quad * 8];
#pragma unroll
    for (int nt = 0; nt < NT; ++nt)
      bfr[nt] = *(const short8*)&Bs[(wn * (NT * 16) + nt * 16 + l15) * 32 + quad * 8];
#pragma unroll
    for (int mt = 0; mt < MT; ++mt)
#pragma unroll
      for (int nt = 0; nt < NT; ++nt)
        acc[mt][nt] = __builtin_amdgcn_mfma_f32_16x16x32_bf16(af[mt], bfr[nt], acc[mt][nt], 0, 0, 0);
    __syncthreads();
  }

#pragma unroll
  for (int nt = 0; nt < NT; ++nt) {
    const int col = blockIdx.x * BN + wn * (NT * 16) + nt * 16 + l15;
    const float bvv = bias ? bias[col] : 0.f;
#pragma unroll
    for (int mt = 0; mt < MT; ++mt) {
#pragma unroll
      for (int r = 0; r < 4; ++r) {
        const int row = blockIdx.y * BM + wm * (MT * 16) + mt * 16 + quad * 4 + r;
        float v = acc[mt][nt][r] + bvv;
        if (relu) v = fmaxf(v, 0.f);
        if (OUTF32) ((float*)Cv)[(long)z * sC + (long)row * ldc + col] = v;
        else        ((u16*)Cv)[(long)z * sC + (long)row * ldc + col] = f2bf(v);
      }
    }
  }
}

// ---------------- 256x256 pipelined bf16 GEMM (T2+T3+T4+T5) --------------------
template<int RELU>
__global__ __launch_bounds__(512, 2) void gemm256_k(
    const u16* __restrict__ A, const u16* __restrict__ Bt,
    const float* __restrict__ bias, u16* __restrict__ C,
    int K, int lda, int ldb, int ldc, int kOff, long sC) {
  __shared__ __align__(16) u16 lds[65536];  // A slots [0,32768) u16, B slots [32768,65536)
  const int bx = blockIdx.x, by = blockIdx.y, z = blockIdx.z;
  A  += (long)z * kOff;
  Bt += (long)z * kOff;
  const int tid = threadIdx.x;
  const int lane = tid & 63, w = tid >> 6;
  const int quad = lane >> 4, l15 = lane & 15;
  const int wm = w >> 2, wn = w & 3;

  const int srow = w * 16 + l15;
  const u16* a0p = A + (long)(by * 256 + srow) * lda + quad * 8;
  const u16* a1p = a0p + (long)128 * lda;
  const u16* b0p = Bt + (long)(bx * 256 + srow) * ldb + quad * 8;
  const u16* b1p = b0p + (long)128 * ldb;

  f32x4 acc[8][4];
#pragma unroll
  for (int i = 0; i < 8; ++i)
#pragma unroll
    for (int j = 0; j < 4; ++j) acc[i][j] = (f32x4){0.f, 0.f, 0.f, 0.f};

  auto STAGE = [&](int c) {
    const int sl = (c & 3) * 8192;
    const long ko = (long)c * 32;
    __builtin_amdgcn_global_load_lds(
        (const __attribute__((address_space(1))) void*)(a0p + ko),
        (__attribute__((address_space(3))) void*)(&lds[sl + tid * 8]), 16, 0, 0);
    __builtin_amdgcn_global_load_lds(
        (const __attribute__((address_space(1))) void*)(a1p + ko),
        (__attribute__((address_space(3))) void*)(&lds[sl + 4096 + tid * 8]), 16, 0, 0);
    __builtin_amdgcn_global_load_lds(
        (const __attribute__((address_space(1))) void*)(b0p + ko),
        (__attribute__((address_space(3))) void*)(&lds[32768 + sl + tid * 8]), 16, 0, 0);
    __builtin_amdgcn_global_load_lds(
        (const __attribute__((address_space(1))) void*)(b1p + ko),
        (__attribute__((address_space(3))) void*)(&lds[32768 + sl + 4096 + tid * 8]), 16, 0, 0);
  };

  auto COMPUTE = [&](int t) {
    const int sl = (t & 3) * 8192;
    short8 af[8], bfv[4];
#pragma unroll
    for (int fr = 0; fr < 8; ++fr)
      af[fr] = *(const short8*)&lds[sl + ((wm * 8 + fr) * 64 + lane) * 8];
#pragma unroll
    for (int fc = 0; fc < 4; ++fc)
      bfv[fc] = *(const short8*)&lds[32768 + sl + ((wn * 4 + fc) * 64 + lane) * 8];
    __builtin_amdgcn_s_setprio(1);
#pragma unroll
    for (int fr = 0; fr < 8; ++fr)
#pragma unroll
      for (int fc = 0; fc < 4; ++fc)
        acc[fr][fc] = __builtin_amdgcn_mfma_f32_16x16x32_bf16(af[fr], bfv[fc], acc[fr][fc], 0, 0, 0);
    __builtin_amdgcn_s_setprio(0);
  };

  const int NT = K >> 5;  // requires NT >= 3
  STAGE(0); STAGE(1); STAGE(2);
  for (int t = 0; t < NT - 2; ++t) {
    asm volatile("s_waitcnt vmcnt(8)" ::: "memory");
    __builtin_amdgcn_s_barrier();
    __builtin_amdgcn_sched_barrier(0);
    if (t + 3 < NT) STAGE(t + 3);
    COMPUTE(t);
  }
  asm volatile("s_waitcnt vmcnt(4)" ::: "memory");
  __builtin_amdgcn_s_barrier();
  __builtin_amdgcn_sched_barrier(0);
  COMPUTE(NT - 2);
  asm volatile("s_waitcnt vmcnt(0)" ::: "memory");
  __builtin_amdgcn_s_barrier();
  __builtin_amdgcn_sched_barrier(0);
  COMPUTE(NT - 1);

  C += (long)z * sC;
#pragma unroll
  for (int fc = 0; fc < 4; ++fc) {
    const int col = bx * 256 + wn * 64 + fc * 16 + l15;
    const float bvv = bias ? bias[col] : 0.f;
#pragma unroll
    for (int fr = 0; fr < 8; ++fr) {
      const long row = by * 256 + wm * 128 + fr * 16 + quad * 4;
#pragma unroll
      for (int r = 0; r < 4; ++r) {
        float v = acc[fr][fc][r] + bvv;
        if (RELU) v = fmaxf(v, 0.f);
        C[(row + r) * ldc + col] = f2bf(v);
      }
    }
  }
}

// ---------------- QKV batched GEMM (m97 structure, 768 blocks; Q pre-scaled) --
__global__ __launch_bounds__(256) void qkv_k(
    const u16* __restrict__ xb, const u16* __restrict__ yb,
    const u16* __restrict__ WqT, const u16* __restrict__ WkT, const u16* __restrict__ WvT,
    const float* __restrict__ bq, const float* __restrict__ bk, const float* __restrict__ bv,
    u16* __restrict__ Q, u16* __restrict__ Kp, u16* __restrict__ Vp) {
  __shared__ __align__(16) u16 As[128 * 32];
  __shared__ __align__(16) u16 Bs[128 * 32];
  const int z = blockIdx.z;
  const u16* A  = (z == 0) ? xb : yb;
  const u16* Bt = (z == 0) ? WqT : (z == 1) ? WkT : WvT;
  const float* bias = (z == 0) ? bq : (z == 1) ? bk : bv;
  u16* C = (z == 0) ? Q : (z == 1) ? Kp : Vp;
  const float sc = (z == 0) ? 0.18033688011112042f : 1.0f;  // 0.125*log2(e)
  const int tid  = threadIdx.x;
  const int lane = tid & 63, wave = tid >> 6;
  const int quad = lane >> 4, l15 = lane & 15;
  const int wm = wave >> 1, wn = wave & 1;
  const u16* Ab = A  + (long)(blockIdx.y * 128) * D_;
  const u16* Bb = Bt + (long)(blockIdx.x * 128) * D_;

  f32x4 acc[4][4];
#pragma unroll
  for (int i = 0; i < 4; ++i)
#pragma unroll
    for (int j = 0; j < 4; ++j) acc[i][j] = (f32x4){0.f, 0.f, 0.f, 0.f};

  const int r0  = tid >> 2;
  const int kk0 = (tid & 3) * 8;

  for (int kt = 0; kt < D_; kt += 32) {
#pragma unroll
    for (int p = 0; p < 2; ++p) {
      __builtin_amdgcn_global_load_lds(
          (const __attribute__((address_space(1))) void*)(Ab + (long)(p * 64 + r0) * D_ + kt + kk0),
          (__attribute__((address_space(3))) void*)(&As[p * 2048 + tid * 8]), 16, 0, 0);
      __builtin_amdgcn_global_load_lds(
          (const __attribute__((address_space(1))) void*)(Bb + (long)(p * 64 + r0) * D_ + kt + kk0),
          (__attribute__((address_space(3))) void*)(&Bs[p * 2048 + tid * 8]), 16, 0, 0);
    }
    __syncthreads();
    short8 af[4], bfr[4];
#pragma unroll
    for (int mt = 0; mt < 4; ++mt)
      af[mt] = *(const short8*)&As[(wm * 64 + mt * 16 + l15) * 32 + quad * 8];
#pragma unroll
    for (int nt = 0; nt < 4; ++nt)
      bfr[nt] = *(const short8*)&Bs[(wn * 64 + nt * 16 + l15) * 32 + quad * 8];
#pragma unroll
    for (int mt = 0; mt < 4; ++mt)
#pragma unroll
      for (int nt = 0; nt < 4; ++nt)
        acc[mt][nt] = __builtin_amdgcn_mfma_f32_16x16x32_bf16(af[mt], bfr[nt], acc[mt][nt], 0, 0, 0);
    __syncthreads();
  }

#pragma unroll
  for (int nt = 0; nt < 4; ++nt) {
    const int col = blockIdx.x * 128 + wn * 64 + nt * 16 + l15;
    const float bvv = bias[col];
#pragma unroll
    for (int mt = 0; mt < 4; ++mt) {
#pragma unroll
      for (int r = 0; r < 4; ++r) {
        const int row = blockIdx.y * 128 + wm * 64 + mt * 16 + quad * 4 + r;
        C[(long)row * D_ + col] = f2bf((acc[mt][nt][r] + bvv) * sc);
      }
    }
  }
}

// ---------------- V[b,s,h*64+d] -> Vt[bh][d][s] ----------------
__global__ void vtrans_k(const u16* __restrict__ V, u16* __restrict__ Vt) {
  __shared__ u16 tile[32][33];
  const int bh = blockIdx.z, b = bh >> 4, h = bh & 15;
  const u16* in = V + (long)b * S_ * D_ + h * DK_;
  u16* outp = Vt + (long)bh * DK_ * S_;
  const int s0 = blockIdx.x * 32, d0 = blockIdx.y * 32;
  const int tx = threadIdx.x, ty = threadIdx.y;
  for (int i = ty; i < 32; i += 8)
    tile[i][tx] = in[(long)(s0 + i) * D_ + d0 + tx];
  __syncthreads();
  for (int i = ty; i < 32; i += 8)
    outp[(long)(d0 + i) * S_ + s0 + tx] = tile[tx][i];
}

// ---------------- fused flash attention v9: QBLK=256, KVBLK=64 ----------------
// grid (B*H=32, S/256=8) = 256 blocks (1/CU), 512 thr (8 waves). Wave w owns
// q rows [w*32,+32). 32 barrier rounds of 64 kv each (v7: 64 rounds of 32) —
// per-round serialization (barrier + ds latency + chain ramp) paid half as
// often. Staging: waves 0-3 stage K (2 slots/thread), waves 4-7 stage V;
// second slot is a uniform +2048 u16 offset for both. P in registers via
// transposed-QK^T / K=16-MFMA pairing; all LDS frag-linear, conflict-free.
__global__ __launch_bounds__(512, 2) void flash_k(
    const u16* __restrict__ Q, const u16* __restrict__ Kp, const u16* __restrict__ Vt,
    const int* __restrict__ mask, u16* __restrict__ ctx) {
  __shared__ __align__(16) u16 sQ[16384];      // 32KB: 32 panels
  __shared__ __align__(16) u16 sK[2][4096];    // 16KB: 2 buf x 8 panels [mk*2+kt]
  __shared__ __align__(16) u16 sV[2][4096];    // 16KB: 2 buf x 512 slots x 16B
  __shared__ int s_allones;

  const int bh = blockIdx.x, qt = blockIdx.y;
  const int b = bh >> 4, h = bh & 15;
  const int tid = threadIdx.x;
  const int w = tid >> 6, lane = tid & 63;
  const int quad = lane >> 4, l15 = lane & 15;

  const u16* Qg  = Q  + ((long)b * S_ + qt * 256) * D_ + h * DK_;
  const u16* Kg  = Kp + (long)b * S_ * D_ + h * DK_;
  const u16* Vtg = Vt + (long)bh * DK_ * S_;
  const int* maskg = mask + (long)b * S_;
  u16* ctxg = ctx + ((long)b * S_ + qt * 256) * D_ + h * DK_;

  // staging: waves 0-3 stage K; waves 4-7 stage V. 2 slots per thread/round.
  const int isK = tid < 256;
  const int t2 = tid & 255;
  const int krow = t2 >> 3, kc = t2 & 7;           // K: rows krow, krow+32
  const int vd  = ((t2 >> 6) << 4) | (t2 & 15);    // V: slots t2, t2+256
  const int vq4 = ((t2 >> 4) & 3) * 4;
  const u16* gptr = isK ? (Kg + (long)krow * D_ + kc * 8)
                        : (Vtg + (long)vd * S_ + vq4);
  const long gstep = isK ? (long)64 * D_ : (long)64;
  const int ksw = (((krow >> 4) * 2 + (kc >> 2)) * 64 + SLOT(kc & 3, krow & 15)) * 8;
  u16* sdst0 = isK ? &sK[0][ksw] : &sV[0][t2 * 8];
  u16* sdst1 = isK ? &sK[1][ksw] : &sV[1][t2 * 8];
  // second slot (K: rows +32 -> panel +4; V: slot +256) = +2048 u16 for both

  uint4 r0_, r1_;
  auto gload2 = [&](const u16* p) {
    if (isK) {
      r0_ = *(const uint4*)p;
      r1_ = *(const uint4*)(p + (long)32 * D_);
    } else {
      uint2 a = *(const uint2*)p,        bb = *(const uint2*)(p + 16);
      uint2 c = *(const uint2*)(p + 32), dd = *(const uint2*)(p + 48);
      r0_ = make_uint4(a.x, a.y, bb.x, bb.y);
      r1_ = make_uint4(c.x, c.y, dd.x, dd.y);
    }
  };

  gload2(gptr);

  // mask all-ones check (block-uniform fast path; masked path kept below)
  int part = 1;
  for (int i = tid; i < S_; i += 512) part &= (maskg[i] != 0);
  if (tid == 0) s_allones = 1;

  // stage Q: 256 rows x 64 cols, frag-linear (4 x uint4 per thread)
#pragma unroll
  for (int p = 0; p < 4; ++p) {
    const int idx = p * 512 + tid;
    const int row = idx >> 3, cb = idx & 7;
    uint4 v = *(const uint4*)(Qg + (long)row * D_ + cb * 8);
    *(uint4*)&sQ[(((row >> 4) * 2 + (cb >> 2)) * 64 + SLOT(cb & 3, row & 15)) * 8] = v;
  }
  *(uint4*)sdst0 = r0_;
  *(uint4*)(sdst0 + 2048) = r1_;
  gload2(gptr + gstep);
  gptr += 2 * gstep;
  __syncthreads();

  const int rslot = SLOT(quad, l15) * 8;   // reader offset within a K/Q panel

  short8 qf[2][2];
#pragma unroll
  for (int mf = 0; mf < 2; ++mf)
#pragma unroll
    for (int kt = 0; kt < 2; ++kt)
      qf[mf][kt] = *(const short8*)&sQ[(((w * 2 + mf) * 2 + kt) * 64) * 8 + rslot];

  if (!part) s_allones = 0;
  __syncthreads();
  const int allones = s_allones;

  float lsum[2] = {0.f, 0.f};
  f32x4 accOT[2][4];   // O^T: [mf][n], col q=l15, rows d = n*16 + quad*4 + r
#pragma unroll
  for (int i = 0; i < 2; ++i)
#pragma unroll
    for (int j = 0; j < 4; ++j) accOT[i][j] = (f32x4){0.f, 0.f, 0.f, 0.f};

  for (int t = 0; t < 32; ++t) {
    if (t) __syncthreads();
    const int buf = t & 1;
    if (t < 31) {
      u16* d = (t & 1) ? sdst0 : sdst1;   // tile t+1 -> buf (t+1)&1
      *(uint4*)d = r0_;
      *(uint4*)(d + 2048) = r1_;
      if (t < 30) {
        gload2(gptr);
        gptr += gstep;
      }
    }
    // scores: Sc^T[kv 64][q 32/wave]; accS[mk] holds kv rows mk*16+quad*4+r
    f32x4 accS[4][2];
#pragma unroll
    for (int i = 0; i < 4; ++i)
#pragma unroll
      for (int j = 0; j < 2; ++j) accS[i][j] = (f32x4){0.f, 0.f, 0.f, 0.f};
#pragma unroll
    for (int kt = 0; kt < 2; ++kt) {
      short8 kf[4];
#pragma unroll
      for (int mk = 0; mk < 4; ++mk)
        kf[mk] = *(const short8*)&sK[buf][((mk * 2 + kt) * 64) * 8 + rslot];
#pragma unroll
      for (int mk = 0; mk < 4; ++mk)
#pragma unroll
        for (int mf = 0; mf < 2; ++mf)
          accS[mk][mf] = __builtin_amdgcn_mfma_f32_16x16x32_bf16(kf[mk], qf[mf][kt], accS[mk][mf], 0, 0, 0);
    }
    // softmax numerator -> P^T bf16, in registers (k=quad*4+r layout)
    s16x4 pb[4][2];
    if (allones) {
#pragma unroll
      for (int mk = 0; mk < 4; ++mk)
#pragma unroll
        for (int mf = 0; mf < 2; ++mf) {
          float p0 = __builtin_amdgcn_exp2f(accS[mk][mf][0]);
          float p1 = __builtin_amdgcn_exp2f(accS[mk][mf][1]);
          float p2 = __builtin_amdgcn_exp2f(accS[mk][mf][2]);
          float p3 = __builtin_amdgcn_exp2f(accS[mk][mf][3]);
          lsum[mf] += (p0 + p1) + (p2 + p3);
          *(uint2*)&pb[mk][mf] = make_uint2(pk2bf(p0, p1), pk2bf(p2, p3));
        }
    } else {
#pragma unroll
      for (int mk = 0; mk < 4; ++mk) {
        const int4 mv = *(const int4*)(maskg + t * 64 + mk * 16 + quad * 4);
#pragma unroll
        for (int mf = 0; mf < 2; ++mf) {
          float p0 = mv.x ? __builtin_amdgcn_exp2f(accS[mk][mf][0]) : 0.f;
          float p1 = mv.y ? __builtin_amdgcn_exp2f(accS[mk][mf][1]) : 0.f;
          float p2 = mv.z ? __builtin_amdgcn_exp2f(accS[mk][mf][2]) : 0.f;
          float p3 = mv.w ? __builtin_amdgcn_exp2f(accS[mk][mf][3]) : 0.f;
          lsum[mf] += (p0 + p1) + (p2 + p3);
          *(uint2*)&pb[mk][mf] = make_uint2(pk2bf(p0, p1), pk2bf(p2, p3));
        }
      }
    }
    // PV: O^T[d 64][q 32] += V^T @ P^T via K=16 MFMA
#pragma unroll
    for (int kp = 0; kp < 2; ++kp) {
#pragma unroll
      for (int n = 0; n < 4; ++n) {
        short8 vv = *(const short8*)&sV[buf][(kp * 256 + n * 64 + lane) * 8];
        s16x4 v0 = __builtin_shufflevector(vv, vv, 0, 1, 2, 3);
        s16x4 v1 = __builtin_shufflevector(vv, vv, 4, 5, 6, 7);
#pragma unroll
        for (int mf = 0; mf < 2; ++mf) {
          accOT[mf][n] = mfma16(v0, pb[kp * 2][mf], accOT[mf][n]);
          accOT[mf][n] = mfma16(v1, pb[kp * 2 + 1][mf], accOT[mf][n]);
        }
      }
    }
  }

  // epilogue: lsum reduce over quads; O^T cols share q=l15 -> per-lane inv
#pragma unroll
  for (int mf = 0; mf < 2; ++mf) {
    lsum[mf] += __shfl_xor(lsum[mf], 16, 64);
    lsum[mf] += __shfl_xor(lsum[mf], 32, 64);
  }
  const float inv0 = 1.f / lsum[0], inv1 = 1.f / lsum[1];
#pragma unroll
  for (int mf = 0; mf < 2; ++mf) {
    const float iv = mf ? inv1 : inv0;
    u16* cp = ctxg + (long)(w * 32 + mf * 16 + l15) * D_;
#pragma unroll
    for (int n = 0; n < 4; ++n) {
      float o0 = accOT[mf][n][0] * iv;
      float o1 = accOT[mf][n][1] * iv;
      float o2 = accOT[mf][n][2] * iv;
      float o3 = accOT[mf][n][3] * iv;
      *(uint2*)(cp + n * 16 + quad * 4) = make_uint2(pk2bf(o0, o1), pk2bf(o2, o3));
    }
  }
}

// ---------------- add + layernorm helpers ----------------
__device__ __forceinline__ float block_reduce_sum(float v, float* red) {
#pragma unroll
  for (int off = 32; off; off >>= 1) v += __shfl_down(v, off, 64);
  __syncthreads();
  if ((threadIdx.x & 63) == 0) red[threadIdx.x >> 6] = v;
  __syncthreads();
  return red[0] + red[1] + red[2] + red[3];
}

// x (fp32) + mha0 + mha1 (bf16 split-K partials) + bo -> LN -> x1 (bf16)
__global__ __launch_bounds__(256) void addln_fb(const float* __restrict__ A,
    const u16* __restrict__ M0, const u16* __restrict__ M1, const float* __restrict__ bo,
    const float* __restrict__ g, const float* __restrict__ be, u16* __restrict__ outp) {
  __shared__ float red[4];
  const int row = blockIdx.x, tid = threadIdx.x;
  const float4 av = ((const float4*)(A + (long)row * D_))[tid];
  const uint2 m0 = ((const uint2*)(M0 + (long)row * D_))[tid];
  const uint2 m1 = ((const uint2*)(M1 + (long)row * D_))[tid];
  const int c0 = tid * 4;
  float xv[4];
  xv[0] = av.x + bf2f((u16)(m0.x & 0xffff)) + bf2f((u16)(m1.x & 0xffff)) + bo[c0 + 0];
  xv[1] = av.y + bf2f((u16)(m0.x >> 16))    + bf2f((u16)(m1.x >> 16))    + bo[c0 + 1];
  xv[2] = av.z + bf2f((u16)(m0.y & 0xffff)) + bf2f((u16)(m1.y & 0xffff)) + bo[c0 + 2];
  xv[3] = av.w + bf2f((u16)(m0.y >> 16))    + bf2f((u16)(m1.y >> 16))    + bo[c0 + 3];
  float s  = xv[0] + xv[1] + xv[2] + xv[3];
  float ss = xv[0]*xv[0] + xv[1]*xv[1] + xv[2]*xv[2] + xv[3]*xv[3];
  s  = block_reduce_sum(s, red);
  ss = block_reduce_sum(ss, red);
  const float m   = s * (1.0f / 1024.0f);
  const float var = ss * (1.0f / 1024.0f) - m * m;
  const float rs  = rsqrtf(var + 1e-5f);
  float v0 = (xv[0] - m) * rs * g[c0 + 0] + be[c0 + 0];
  float v1 = (xv[1] - m) * rs * g[c0 + 1] + be[c0 + 1];
  float v2 = (xv[2] - m) * rs * g[c0 + 2] + be[c0 + 2];
  float v3 = (xv[3] - m) * rs * g[c0 + 3] + be[c0 + 3];
  unsigned int o01 = (unsigned int)f2bf(v0) | ((unsigned int)f2bf(v1) << 16);
  unsigned int o23 = (unsigned int)f2bf(v2) | ((unsigned int)f2bf(v3) << 16);
  ((uint2*)(outp + (long)row * D_))[tid] = make_uint2(o01, o23);
}

// x1 (bf16) + ff0..ff3 (bf16 split-K partials) + b2 -> LN -> out (fp32)
__global__ __launch_bounds__(256) void addln2_bf(const u16* __restrict__ A,
    const u16* __restrict__ F0, const u16* __restrict__ F1,
    const u16* __restrict__ F2, const u16* __restrict__ F3,
    const float* __restrict__ b2,
    const float* __restrict__ g, const float* __restrict__ be, float* __restrict__ outp) {
  __shared__ float red[4];
  const int row = blockIdx.x, tid = threadIdx.x;
  const uint2 av = ((const uint2*)(A + (long)row * D_))[tid];
  const uint2 f0 = ((const uint2*)(F0 + (long)row * D_))[tid];
  const uint2 f1 = ((const uint2*)(F1 + (long)row * D_))[tid];
  const uint2 f2 = ((const uint2*)(F2 + (long)row * D_))[tid];
  const uint2 f3 = ((const uint2*)(F3 + (long)row * D_))[tid];
  const int c0 = tid * 4;
  float xv[4];
  xv[0] = bf2f((u16)(av.x & 0xffff)) + bf2f((u16)(f0.x & 0xffff)) + bf2f((u16)(f1.x & 0xffff))
        + bf2f((u16)(f2.x & 0xffff)) + bf2f((u16)(f3.x & 0xffff)) + b2[c0 + 0];
  xv[1] = bf2f((u16)(av.x >> 16))    + bf2f((u16)(f0.x >> 16))    + bf2f((u16)(f1.x >> 16))
        + bf2f((u16)(f2.x >> 16))    + bf2f((u16)(f3.x >> 16))    + b2[c0 + 1];
  xv[2] = bf2f((u16)(av.y & 0xffff)) + bf2f((u16)(f0.y & 0xffff)) + bf2f((u16)(f1.y & 0xffff))
        + bf2f((u16)(f2.y & 0xffff)) + bf2f((u16)(f3.y & 0xffff)) + b2[c0 + 2];
  xv[3] = bf2f((u16)(av.y >> 16))    + bf2f((u16)(f0.y >> 16))    + bf2f((u16)(f1.y >> 16))
        + bf2f((u16)(f2.y >> 16))    + bf2f((u16)(f3.y >> 16))    + b2[c0 + 3];
  float s  = xv[0] + xv[1] + xv[2] + xv[3];
  float ss = xv[0]*xv[0] + xv[1]*xv[1] + xv[2]*xv[2] + xv[3]*xv[3];
  s  = block_reduce_sum(s, red);
  ss = block_reduce_sum(ss, red);
  const float m   = s * (1.0f / 1024.0f);
  const float var = ss * (1.0f / 1024.0f) - m * m;
  const float rs  = rsqrtf(var + 1e-5f);
  float4 o;
  o.x = (xv[0] - m) * rs * g[c0 + 0] + be[c0 + 0];
  o.y = (xv[1] - m) * rs * g[c0 + 1] + be[c0 + 1];
  o.z = (xv[2] - m) * rs * g[c0 + 2] + be[c0 + 2];
  o.w = (xv[3] - m) * rs * g[c0 + 3] + be[c0 + 3];
  ((float4*)(outp + (long)row * D_))[tid] = o;
}

extern "C" void kernel_launch(void* const* d_in, const int* in_sizes, int n_in,
                              void* d_out, int out_size, void* d_ws, size_t ws_size,
                              hipStream_t stream) {
  const float* x   = (const float*)d_in[0];
  const float* y   = (const float*)d_in[1];
  const int* mask  = (const int*)d_in[2];
  const float* Wq = (const float*)d_in[3];  const float* bq = (const float*)d_in[4];
  const float* Wk = (const float*)d_in[5];  const float* bk = (const float*)d_in[6];
  const float* Wv = (const float*)d_in[7];  const float* bv = (const float*)d_in[8];
  const float* Wo = (const float*)d_in[9];  const float* bo = (const float*)d_in[10];
  const float* W1 = (const float*)d_in[11]; const float* b1 = (const float*)d_in[12];
  const float* W2 = (const float*)d_in[13]; const float* b2 = (const float*)d_in[14];
  const float* g1 = (const float*)d_in[15]; const float* be1 = (const float*)d_in[16];
  const float* g2 = (const float*)d_in[17]; const float* be2 = (const float*)d_in[18];
  float* out = (float*)d_out;

  char* w = (char*)d_ws;
  const size_t MB = 1024 * 1024;
  u16* WqT = (u16*)(w + 0 * MB);
  u16* WkT = (u16*)(w + 2 * MB);
  u16* WvT = (u16*)(w + 4 * MB);
  u16* WoT = (u16*)(w + 6 * MB);
  u16* W1T = (u16*)(w + 8 * MB);     // 8MB  [HID][D]
  u16* W2T = (u16*)(w + 16 * MB);    // 8MB  [D][HID]
  u16* xb  = (u16*)(w + 24 * MB);    // dead after qkv; x1 reuses
  u16* yb  = (u16*)(w + 32 * MB);    // dead after qkv
  u16* Q   = (u16*)(w + 40 * MB);    // dead after flash; ff partials reuse
  u16* Kp  = (u16*)(w + 48 * MB);    // dead after flash
  u16* Vp  = (u16*)(w + 56 * MB);    // dead after vtrans
  u16* Vt  = (u16*)(w + 64 * MB);    // dead after flash
  u16* ctx = (u16*)(w + 72 * MB);    // dead after Wo gemm
  u16* mha = (u16*)(w + 80 * MB);    // 2 x 8MB bf16 split-K partials (80..96)
  u16* x1  = (u16*)(w + 24 * MB);    // reuses xb; live through addln2
  u16* h1  = (u16*)(w + 96 * MB);    // 32MB bf16 [4096][4096]
  u16* ff  = (u16*)(w + 40 * MB);    // 4 x 8MB bf16 split-K partials (40..72)

  // prep: 6 weight transposes + 2 activation cvts, ONE dispatch
  prep8_k<<<dim3(128, 32, 8), dim3(32, 8), 0, stream>>>(Wq, Wk, Wv, Wo, W1, W2,
      x, y, WqT, WkT, WvT, WoT, W1T, W2T, xb, yb);

  // QKV: m97 structure, 768 blocks (high TLP wins at skinny N; R2 post-mortem)
  qkv_k<<<dim3(8, 32, 3), 256, 0, stream>>>(xb, yb, WqT, WkT, WvT, bq, bk, bv, Q, Kp, Vp);

  vtrans_k<<<dim3(64, 2, 32), dim3(32, 8), 0, stream>>>(Vp, Vt);

  // fused flash attention v9: QBLK=256, KVBLK=64, 256 blocks (1/CU)
  flash_k<<<dim3(32, 8), 512, 0, stream>>>(Q, Kp, Vt, mask, ctx);

  // output projection: split-K=2 on gemm_bt (512 blocks); bo folded into LN1
  gemm_bt<4, 4, 0><<<dim3(8, 32, 2), 256, 0, stream>>>(ctx, WoT, nullptr, mha,
      512, 1024, 1024, 1024, 512, 512, (long)4096 * 1024, 0);
  addln_fb<<<dim3(4096), 256, 0, stream>>>(x, mha, mha + (long)4096 * 1024, bo, g1, be1, x1);

  // FFN1: 256 blocks, pipelined 256x256 kernel
  gemm256_k<1><<<dim3(16, 16, 1), 512, 0, stream>>>(x1, W1T, b1, h1,
      1024, 1024, 1024, 4096, 0, 0);
  // FFN2: split-K=4, bf16 partials (256 blocks); b2 folded into LN2
  gemm256_k<0><<<dim3(4, 16, 4), 512, 0, stream>>>(h1, W2T, nullptr, ff,
      1024, 4096, 4096, 1024, 1024, (long)4096 * 1024);
  addln2_bf<<<dim3(4096), 256, 0, stream>>>(x1, ff, ff + (long)4096 * 1024,
      ff + (long)2 * 4096 * 1024, ff + (long)3 * 4096 * 1024, b2, g2, be2, out);
}

// Round 8
// 388.781 us; speedup vs baseline: 1.0442x; 1.0036x over previous
//
#include <hip/hip_runtime.h>

#define S_ 2048
#define D_ 1024
#define B_ 2
#define H_ 16
#define DK_ 64
#define HID_ 4096

typedef unsigned short u16;
typedef __attribute__((ext_vector_type(8))) short short8;
typedef __attribute__((ext_vector_type(4))) short s16x4;
typedef __attribute__((ext_vector_type(4))) float f32x4;

// frag-linear slot with bank-spreading XOR: panel of 64 slots x 16B
#define SLOT(q16, r16) (((q16) * 16) + ((r16) ^ (q16)))

__device__ __forceinline__ float bf2f(u16 u) {
  return __uint_as_float(((unsigned int)u) << 16);
}
__device__ __forceinline__ u16 f2bf(float f) {
  unsigned int x = __float_as_uint(f);
  x += 0x7fff + ((x >> 16) & 1);
  return (u16)(x >> 16);
}
__device__ __forceinline__ unsigned int pk2bf(float lo, float hi) {
  return ((__float_as_uint(lo) + 0x8000u) >> 16) | ((__float_as_uint(hi) + 0x8000u) & 0xffff0000u);
}

// K=16 bf16 MFMA: B-operand k-layout (k=quad*4+j) matches the C-layout of a
// prior MFMA (rows quad*4+r) -> P^T feeds PV directly from registers.
__device__ __forceinline__ f32x4 mfma16(s16x4 a, s16x4 b, f32x4 c) {
#if __has_builtin(__builtin_amdgcn_mfma_f32_16x16x16_bf16)
  return __builtin_amdgcn_mfma_f32_16x16x16_bf16(a, b, c, 0, 0, 0);
#else
  return __builtin_amdgcn_mfma_f32_16x16x16bf16_1k(a, b, c, 0, 0, 0);
#endif
}

// ---------------- prep: 6 weight transposes + 2 activation cvts (one dispatch)
__global__ void prep8_k(
    const float* __restrict__ Wq, const float* __restrict__ Wk,
    const float* __restrict__ Wv, const float* __restrict__ Wo,
    const float* __restrict__ W1, const float* __restrict__ W2,
    const float* __restrict__ x, const float* __restrict__ y,
    u16* __restrict__ WqT, u16* __restrict__ WkT, u16* __restrict__ WvT,
    u16* __restrict__ WoT, u16* __restrict__ W1T, u16* __restrict__ W2T,
    u16* __restrict__ xb, u16* __restrict__ yb) {
  __shared__ u16 tile[32][33];
  const int z = blockIdx.z;
  const int tx = threadIdx.x, ty = threadIdx.y;
  if (z >= 6) {
    const float* in = (z == 7) ? y : x;
    u16* outp = (z == 7) ? yb : xb;
    const int tid = ty * 32 + tx;
    const long i = ((long)blockIdx.y * 128 + blockIdx.x) * 256 + tid;
    float4 v = ((const float4*)in)[i];
    unsigned int lo = (unsigned int)f2bf(v.x) | ((unsigned int)f2bf(v.y) << 16);
    unsigned int hi = (unsigned int)f2bf(v.z) | ((unsigned int)f2bf(v.w) << 16);
    ((uint2*)outp)[i] = make_uint2(lo, hi);
    return;
  }
  const float* in; u16* outp; int R, C;
  switch (z) {
    case 0: in = Wq; outp = WqT; R = 1024; C = 1024; break;
    case 1: in = Wk; outp = WkT; R = 1024; C = 1024; break;
    case 2: in = Wv; outp = WvT; R = 1024; C = 1024; break;
    case 3: in = Wo; outp = WoT; R = 1024; C = 1024; break;
    case 4: in = W1; outp = W1T; R = 1024; C = 4096; break;
    default: in = W2; outp = W2T; R = 4096; C = 1024; break;
  }
  int c0, r0;
  if (z == 5) { c0 = blockIdx.y * 32; r0 = blockIdx.x * 32; }
  else        { c0 = blockIdx.x * 32; r0 = blockIdx.y * 32; }
  if (c0 >= C || r0 >= R) return;
  for (int i = ty; i < 32; i += 8)
    tile[i][tx] = f2bf(in[(long)(r0 + i) * C + c0 + tx]);
  __syncthreads();
  for (int i = ty; i < 32; i += 8)
    outp[(long)(c0 + i) * R + r0 + tx] = tile[tx][i];
}

// ---------------- generic bf16 GEMM: C[M,N] = A[M,K] @ Bt[N,K]^T ----------------
// m97 structure, high-TLP: best for skinny-N shapes (many small blocks).
template<int MT, int NT, int OUTF32>
__global__ __launch_bounds__(256) void gemm_bt(
    const u16* __restrict__ A, const u16* __restrict__ Bt,
    const float* __restrict__ bias, void* __restrict__ Cv,
    int K, int lda, int ldb, int ldc,
    long sA, long sB, long sC, int relu) {
  constexpr int BM = MT * 32;
  constexpr int BN = NT * 32;
  __shared__ __align__(16) u16 As[BM * 32];
  __shared__ __align__(16) u16 Bs[BN * 32];
  const int z = blockIdx.z;
  A  += (long)z * sA;
  Bt += (long)z * sB;
  const int tid  = threadIdx.x;
  const int lane = tid & 63, wave = tid >> 6;
  const int quad = lane >> 4, l15 = lane & 15;
  const int wm = wave >> 1, wn = wave & 1;
  const u16* Ab = A  + (long)(blockIdx.y * BM) * lda;
  const u16* Bb = Bt + (long)(blockIdx.x * BN) * ldb;

  f32x4 acc[MT][NT];
#pragma unroll
  for (int i = 0; i < MT; ++i)
#pragma unroll
    for (int j = 0; j < NT; ++j) acc[i][j] = (f32x4){0.f, 0.f, 0.f, 0.f};

  const int r0  = tid >> 2;
  const int kk0 = (tid & 3) * 8;

  for (int kt = 0; kt < K; kt += 32) {
#pragma unroll
    for (int p = 0; p < BM / 64; ++p) {
      __builtin_amdgcn_global_load_lds(
          (const __attribute__((address_space(1))) void*)(Ab + (long)(p * 64 + r0) * lda + kt + kk0),
          (__attribute__((address_space(3))) void*)(&As[p * 2048 + tid * 8]), 16, 0, 0);
    }
#pragma unroll
    for (int p = 0; p < BN / 64; ++p) {
      __builtin_amdgcn_global_load_lds(
          (const __attribute__((address_space(1))) void*)(Bb + (long)(p * 64 + r0) * ldb + kt + kk0),
          (__attribute__((address_space(3))) void*)(&Bs[p * 2048 + tid * 8]), 16, 0, 0);
    }
    __syncthreads();
    short8 af[MT], bfr[NT];
#pragma unroll
    for (int mt = 0; mt < MT; ++mt)
      af[mt] = *(const short8*)&As[(wm * (MT * 16) + mt * 16 + l15) * 32 + quad * 8];
#pragma unroll
    for (int nt = 0; nt < NT; ++nt)
      bfr[nt] = *(const short8*)&Bs[(wn * (NT * 16) + nt * 16 + l15) * 32 + quad * 8];
#pragma unroll
    for (int mt = 0; mt < MT; ++mt)
#pragma unroll
      for (int nt = 0; nt < NT; ++nt)
        acc[mt][nt] = __builtin_amdgcn_mfma_f32_16x16x32_bf16(af[mt], bfr[nt], acc[mt][nt], 0, 0, 0);
    __syncthreads();
  }

#pragma unroll
  for (int nt = 0; nt < NT; ++nt) {
    const int col = blockIdx.x * BN + wn * (NT * 16) + nt * 16 + l15;
    const float bvv = bias ? bias[col] : 0.f;
#pragma unroll
    for (int mt = 0; mt < MT; ++mt) {
#pragma unroll
      for (int r = 0; r < 4; ++r) {
        const int row = blockIdx.y * BM + wm * (MT * 16) + mt * 16 + quad * 4 + r;
        float v = acc[mt][nt][r] + bvv;
        if (relu) v = fmaxf(v, 0.f);
        if (OUTF32) ((float*)Cv)[(long)z * sC + (long)row * ldc + col] = v;
        else        ((u16*)Cv)[(long)z * sC + (long)row * ldc + col] = f2bf(v);
      }
    }
  }
}

// ---------------- 256x256 8-phase pipelined bf16 GEMM (T2+T3+T4+T5) ------------
// The verified m201 schedule, plain-HIP port. 512 thr = 8 waves (2M x 4N),
// per-wave C = 128x64. BK=64 per K-tile; 2 LDS buffers x 64KB (A,B x 2 halves
// x 128x64 bf16), frag-linear (gload_lds linear dest -> conflict-free reads).
// 4 phases per K-tile: {ds_read subtile || stage 2 gload_lds -> barrier ->
// lgkmcnt(0) -> setprio(1) 16 MFMA setprio(0) -> barrier}. Stages for K-tile
// t+2 land in buf t&1, each region issued the phase AFTER its last read
// (barrier-separated -> race-free). K-tile boundary wait = vmcnt(6)
// (2 loads/half-tile x 3 in flight; never 0 except before the last K-tile).
template<int RELU>
__global__ __launch_bounds__(512, 2) void gemm8p_k(
    const u16* __restrict__ A, const u16* __restrict__ Bt,
    const float* __restrict__ bias, u16* __restrict__ C,
    int K, int lda, int ldb, int ldc, int kOff, long sC) {
  __shared__ __align__(16) u16 lds[65536];  // 128KB: buf d*32768; A [0,16384), B [16384,32768)
  const int bx = blockIdx.x, by = blockIdx.y, z = blockIdx.z;
  A  += (long)z * kOff;
  Bt += (long)z * kOff;
  const int tid = threadIdx.x;
  const int lane = tid & 63, w = tid >> 6;
  const int quad = lane >> 4, l15 = lane & 15;
  const int h = w >> 2, fw = w & 3;   // staging coords (h also = compute wm)
  const int wm = h, wn = w & 3;

  // staging global bases: A rows by*256 + h*128 + fw*16 + l15 (+g*64);
  // B cols bx*256 + h*128 + (fw>>1)*64 + (fw&1)*16 + l15 (+gB*32)
  const u16* aSt = A  + (long)(by * 256 + h * 128 + fw * 16 + l15) * lda + quad * 8;
  const u16* bSt = Bt + (long)(bx * 256 + h * 128 + (fw >> 1) * 64 + (fw & 1) * 16 + l15) * ldb + quad * 8;
  const int pp0 = (fw >> 1) * 4 + (fw & 1);   // B panel for gB=0 (gB adds 2)
  const int NTK = K >> 6;

  f32x4 acc[8][4];
#pragma unroll
  for (int i = 0; i < 8; ++i)
#pragma unroll
    for (int j = 0; j < 4; ++j) acc[i][j] = (f32x4){0.f, 0.f, 0.f, 0.f};

  // 2 issues (kt=0,1): A group g (frs g*4..g*4+3 of both halves), K-tile t
  auto STAGE_A = [&](int t, int g) {
    if (t >= NTK) return;
    const int b0 = (t & 1) * 32768 + h * 6144 + g * 4096 + fw * 512;
    const u16* p = aSt + (long)t * 64 + (long)g * 64 * lda;
    __builtin_amdgcn_global_load_lds(
        (const __attribute__((address_space(1))) void*)p,
        (__attribute__((address_space(3))) void*)(&lds[b0 + tid * 8]), 16, 0, 0);
    __builtin_amdgcn_global_load_lds(
        (const __attribute__((address_space(1))) void*)(p + 32),
        (__attribute__((address_space(3))) void*)(&lds[b0 + 512 + tid * 8]), 16, 0, 0);
  };
  // B group gB: gB=0 -> panels {0,1,4,5}, gB=1 -> {2,3,6,7}
  auto STAGE_B = [&](int t, int gB) {
    if (t >= NTK) return;
    const int pp = pp0 + gB * 2;
    const int b0 = (t & 1) * 32768 + 16384 + h * 6144 + pp * 1024 - fw * 512;
    const u16* p = bSt + (long)t * 64 + (long)gB * 32 * ldb;
    __builtin_amdgcn_global_load_lds(
        (const __attribute__((address_space(1))) void*)p,
        (__attribute__((address_space(3))) void*)(&lds[b0 + tid * 8]), 16, 0, 0);
    __builtin_amdgcn_global_load_lds(
        (const __attribute__((address_space(1))) void*)(p + 32),
        (__attribute__((address_space(3))) void*)(&lds[b0 + 512 + tid * 8]), 16, 0, 0);
  };

  // prologue: t0 full (8) + t1 first 6, steady-state order
  STAGE_A(0, 0); STAGE_A(0, 1); STAGE_B(0, 0); STAGE_B(0, 1);
  STAGE_A(1, 0); STAGE_B(1, 0); STAGE_A(1, 1);

  short8 afL[4][2], afH[4][2], bfL[2][2], bfH[2][2];
  const int aRd = wm * 8192 + lane * 8;                       // + d + (fr*2+kt)*512
  const int bRd = 16384 + (wn >> 1) * 8192 + lane * 8;        // + d + (p*2+kt)*512
  const int bP  = (wn & 1) * 4;

  for (int t = 0; t < NTK; ++t) {
    // K-tile boundary: buf t fully landed; 6 loads (t+1's first 3 half-tiles) in flight
    if (t == NTK - 1) asm volatile("s_waitcnt vmcnt(0)" ::: "memory");
    else              asm volatile("s_waitcnt vmcnt(6)" ::: "memory");
    __builtin_amdgcn_s_barrier();
    __builtin_amdgcn_sched_barrier(0);
    const int d = (t & 1) * 32768;

    // ---- phase 1: read q0 frags (A fr0-3, B fc0-1); stage B gB1 (t+1)
#pragma unroll
    for (int fr = 0; fr < 4; ++fr)
#pragma unroll
      for (int kt = 0; kt < 2; ++kt)
        afL[fr][kt] = *(const short8*)&lds[d + aRd + (fr * 2 + kt) * 512];
#pragma unroll
    for (int fc = 0; fc < 2; ++fc)
#pragma unroll
      for (int kt = 0; kt < 2; ++kt)
        bfL[fc][kt] = *(const short8*)&lds[d + bRd + ((bP + fc) * 2 + kt) * 512];
    STAGE_B(t + 1, 1);
    __builtin_amdgcn_s_barrier();
    asm volatile("s_waitcnt lgkmcnt(0)" ::: "memory");
    __builtin_amdgcn_sched_barrier(0);
    __builtin_amdgcn_s_setprio(1);
#pragma unroll
    for (int fr = 0; fr < 4; ++fr)
#pragma unroll
      for (int fc = 0; fc < 2; ++fc)
#pragma unroll
        for (int kt = 0; kt < 2; ++kt)
          acc[fr][fc] = __builtin_amdgcn_mfma_f32_16x16x32_bf16(afL[fr][kt], bfL[fc][kt], acc[fr][fc], 0, 0, 0);
    __builtin_amdgcn_s_setprio(0);
    __builtin_amdgcn_s_barrier();
    __builtin_amdgcn_sched_barrier(0);

    // ---- phase 2: read B fc2-3; stage A g0 (t+2)
#pragma unroll
    for (int fc = 0; fc < 2; ++fc)
#pragma unroll
      for (int kt = 0; kt < 2; ++kt)
        bfH[fc][kt] = *(const short8*)&lds[d + bRd + ((bP + 2 + fc) * 2 + kt) * 512];
    STAGE_A(t + 2, 0);
    __builtin_amdgcn_s_barrier();
    asm volatile("s_waitcnt lgkmcnt(0)" ::: "memory");
    __builtin_amdgcn_sched_barrier(0);
    __builtin_amdgcn_s_setprio(1);
#pragma unroll
    for (int fr = 0; fr < 4; ++fr)
#pragma unroll
      for (int fc = 0; fc < 2; ++fc)
#pragma unroll
        for (int kt = 0; kt < 2; ++kt)
          acc[fr][fc + 2] = __builtin_amdgcn_mfma_f32_16x16x32_bf16(afL[fr][kt], bfH[fc][kt], acc[fr][fc + 2], 0, 0, 0);
    __builtin_amdgcn_s_setprio(0);
    __builtin_amdgcn_s_barrier();
    __builtin_amdgcn_sched_barrier(0);

    // ---- phase 3: read A fr4-7; stage B gB0 (t+2)
#pragma unroll
    for (int fr = 0; fr < 4; ++fr)
#pragma unroll
      for (int kt = 0; kt < 2; ++kt)
        afH[fr][kt] = *(const short8*)&lds[d + aRd + ((4 + fr) * 2 + kt) * 512];
    STAGE_B(t + 2, 0);
    __builtin_amdgcn_s_barrier();
    asm volatile("s_waitcnt lgkmcnt(0)" ::: "memory");
    __builtin_amdgcn_sched_barrier(0);
    __builtin_amdgcn_s_setprio(1);
#pragma unroll
    for (int fr = 0; fr < 4; ++fr)
#pragma unroll
      for (int fc = 0; fc < 2; ++fc)
#pragma unroll
        for (int kt = 0; kt < 2; ++kt)
          acc[fr + 4][fc] = __builtin_amdgcn_mfma_f32_16x16x32_bf16(afH[fr][kt], bfL[fc][kt], acc[fr + 4][fc], 0, 0, 0);
    __builtin_amdgcn_s_setprio(0);
    __builtin_amdgcn_s_barrier();
    __builtin_amdgcn_sched_barrier(0);

    // ---- phase 4: no reads; stage A g1 (t+2); trailing barrier = loop-top
    STAGE_A(t + 2, 1);
    __builtin_amdgcn_s_barrier();
    __builtin_amdgcn_sched_barrier(0);
    __builtin_amdgcn_s_setprio(1);
#pragma unroll
    for (int fr = 0; fr < 4; ++fr)
#pragma unroll
      for (int fc = 0; fc < 2; ++fc)
#pragma unroll
        for (int kt = 0; kt < 2; ++kt)
          acc[fr + 4][fc + 2] = __builtin_amdgcn_mfma_f32_16x16x32_bf16(afH[fr][kt], bfH[fc][kt], acc[fr + 4][fc + 2], 0, 0, 0);
    __builtin_amdgcn_s_setprio(0);
    // barrier2 of phase 4 = next iteration's boundary barrier (or epilogue)
  }

  C += (long)z * sC;
#pragma unroll
  for (int fc = 0; fc < 4; ++fc) {
    const int col = bx * 256 + wn * 64 + fc * 16 + l15;
    const float bvv = bias ? bias[col] : 0.f;
#pragma unroll
    for (int fr = 0; fr < 8; ++fr) {
      const long row = by * 256 + wm * 128 + fr * 16 + quad * 4;
#pragma unroll
      for (int r = 0; r < 4; ++r) {
        float v = acc[fr][fc][r] + bvv;
        if (RELU) v = fmaxf(v, 0.f);
        C[(row + r) * ldc + col] = f2bf(v);
      }
    }
  }
}

// ---------------- QKV batched GEMM (m97 structure, 768 blocks; Q pre-scaled) --
__global__ __launch_bounds__(256) void qkv_k(
    const u16* __restrict__ xb, const u16* __restrict__ yb,
    const u16* __restrict__ WqT, const u16* __restrict__ WkT, const u16* __restrict__ WvT,
    const float* __restrict__ bq, const float* __restrict__ bk, const float* __restrict__ bv,
    u16* __restrict__ Q, u16* __restrict__ Kp, u16* __restrict__ Vp) {
  __shared__ __align__(16) u16 As[128 * 32];
  __shared__ __align__(16) u16 Bs[128 * 32];
  const int z = blockIdx.z;
  const u16* A  = (z == 0) ? xb : yb;
  const u16* Bt = (z == 0) ? WqT : (z == 1) ? WkT : WvT;
  const float* bias = (z == 0) ? bq : (z == 1) ? bk : bv;
  u16* C = (z == 0) ? Q : (z == 1) ? Kp : Vp;
  const float sc = (z == 0) ? 0.18033688011112042f : 1.0f;  // 0.125*log2(e)
  const int tid  = threadIdx.x;
  const int lane = tid & 63, wave = tid >> 6;
  const int quad = lane >> 4, l15 = lane & 15;
  const int wm = wave >> 1, wn = wave & 1;
  const u16* Ab = A  + (long)(blockIdx.y * 128) * D_;
  const u16* Bb = Bt + (long)(blockIdx.x * 128) * D_;

  f32x4 acc[4][4];
#pragma unroll
  for (int i = 0; i < 4; ++i)
#pragma unroll
    for (int j = 0; j < 4; ++j) acc[i][j] = (f32x4){0.f, 0.f, 0.f, 0.f};

  const int r0  = tid >> 2;
  const int kk0 = (tid & 3) * 8;

  for (int kt = 0; kt < D_; kt += 32) {
#pragma unroll
    for (int p = 0; p < 2; ++p) {
      __builtin_amdgcn_global_load_lds(
          (const __attribute__((address_space(1))) void*)(Ab + (long)(p * 64 + r0) * D_ + kt + kk0),
          (__attribute__((address_space(3))) void*)(&As[p * 2048 + tid * 8]), 16, 0, 0);
      __builtin_amdgcn_global_load_lds(
          (const __attribute__((address_space(1))) void*)(Bb + (long)(p * 64 + r0) * D_ + kt + kk0),
          (__attribute__((address_space(3))) void*)(&Bs[p * 2048 + tid * 8]), 16, 0, 0);
    }
    __syncthreads();
    short8 af[4], bfr[4];
#pragma unroll
    for (int mt = 0; mt < 4; ++mt)
      af[mt] = *(const short8*)&As[(wm * 64 + mt * 16 + l15) * 32 + quad * 8];
#pragma unroll
    for (int nt = 0; nt < 4; ++nt)
      bfr[nt] = *(const short8*)&Bs[(wn * 64 + nt * 16 + l15) * 32 + quad * 8];
#pragma unroll
    for (int mt = 0; mt < 4; ++mt)
#pragma unroll
      for (int nt = 0; nt < 4; ++nt)
        acc[mt][nt] = __builtin_amdgcn_mfma_f32_16x16x32_bf16(af[mt], bfr[nt], acc[mt][nt], 0, 0, 0);
    __syncthreads();
  }

#pragma unroll
  for (int nt = 0; nt < 4; ++nt) {
    const int col = blockIdx.x * 128 + wn * 64 + nt * 16 + l15;
    const float bvv = bias[col];
#pragma unroll
    for (int mt = 0; mt < 4; ++mt) {
#pragma unroll
      for (int r = 0; r < 4; ++r) {
        const int row = blockIdx.y * 128 + wm * 64 + mt * 16 + quad * 4 + r;
        C[(long)row * D_ + col] = f2bf((acc[mt][nt][r] + bvv) * sc);
      }
    }
  }
}

// ---------------- V[b,s,h*64+d] -> Vt[bh][d][s] ----------------
__global__ void vtrans_k(const u16* __restrict__ V, u16* __restrict__ Vt) {
  __shared__ u16 tile[32][33];
  const int bh = blockIdx.z, b = bh >> 4, h = bh & 15;
  const u16* in = V + (long)b * S_ * D_ + h * DK_;
  u16* outp = Vt + (long)bh * DK_ * S_;
  const int s0 = blockIdx.x * 32, d0 = blockIdx.y * 32;
  const int tx = threadIdx.x, ty = threadIdx.y;
  for (int i = ty; i < 32; i += 8)
    tile[i][tx] = in[(long)(s0 + i) * D_ + d0 + tx];
  __syncthreads();
  for (int i = ty; i < 32; i += 8)
    outp[(long)(d0 + i) * S_ + s0 + tx] = tile[tx][i];
}

// ---------------- fused flash attention v9: QBLK=256, KVBLK=64 ----------------
__global__ __launch_bounds__(512, 2) void flash_k(
    const u16* __restrict__ Q, const u16* __restrict__ Kp, const u16* __restrict__ Vt,
    const int* __restrict__ mask, u16* __restrict__ ctx) {
  __shared__ __align__(16) u16 sQ[16384];      // 32KB: 32 panels
  __shared__ __align__(16) u16 sK[2][4096];    // 16KB: 2 buf x 8 panels [mk*2+kt]
  __shared__ __align__(16) u16 sV[2][4096];    // 16KB: 2 buf x 512 slots x 16B
  __shared__ int s_allones;

  const int bh = blockIdx.x, qt = blockIdx.y;
  const int b = bh >> 4, h = bh & 15;
  const int tid = threadIdx.x;
  const int w = tid >> 6, lane = tid & 63;
  const int quad = lane >> 4, l15 = lane & 15;

  const u16* Qg  = Q  + ((long)b * S_ + qt * 256) * D_ + h * DK_;
  const u16* Kg  = Kp + (long)b * S_ * D_ + h * DK_;
  const u16* Vtg = Vt + (long)bh * DK_ * S_;
  const int* maskg = mask + (long)b * S_;
  u16* ctxg = ctx + ((long)b * S_ + qt * 256) * D_ + h * DK_;

  // staging: waves 0-3 stage K; waves 4-7 stage V. 2 slots per thread/round.
  const int isK = tid < 256;
  const int t2 = tid & 255;
  const int krow = t2 >> 3, kc = t2 & 7;           // K: rows krow, krow+32
  const int vd  = ((t2 >> 6) << 4) | (t2 & 15);    // V: slots t2, t2+256
  const int vq4 = ((t2 >> 4) & 3) * 4;
  const u16* gptr = isK ? (Kg + (long)krow * D_ + kc * 8)
                        : (Vtg + (long)vd * S_ + vq4);
  const long gstep = isK ? (long)64 * D_ : (long)64;
  const int ksw = (((krow >> 4) * 2 + (kc >> 2)) * 64 + SLOT(kc & 3, krow & 15)) * 8;
  u16* sdst0 = isK ? &sK[0][ksw] : &sV[0][t2 * 8];
  u16* sdst1 = isK ? &sK[1][ksw] : &sV[1][t2 * 8];
  // second slot (K: rows +32 -> panel +4; V: slot +256) = +2048 u16 for both

  uint4 r0_, r1_;
  auto gload2 = [&](const u16* p) {
    if (isK) {
      r0_ = *(const uint4*)p;
      r1_ = *(const uint4*)(p + (long)32 * D_);
    } else {
      uint2 a = *(const uint2*)p,        bb = *(const uint2*)(p + 16);
      uint2 c = *(const uint2*)(p + 32), dd = *(const uint2*)(p + 48);
      r0_ = make_uint4(a.x, a.y, bb.x, bb.y);
      r1_ = make_uint4(c.x, c.y, dd.x, dd.y);
    }
  };

  gload2(gptr);

  // mask all-ones check (block-uniform fast path; masked path kept below)
  int part = 1;
  for (int i = tid; i < S_; i += 512) part &= (maskg[i] != 0);
  if (tid == 0) s_allones = 1;

  // stage Q: 256 rows x 64 cols, frag-linear (4 x uint4 per thread)
#pragma unroll
  for (int p = 0; p < 4; ++p) {
    const int idx = p * 512 + tid;
    const int row = idx >> 3, cb = idx & 7;
    uint4 v = *(const uint4*)(Qg + (long)row * D_ + cb * 8);
    *(uint4*)&sQ[(((row >> 4) * 2 + (cb >> 2)) * 64 + SLOT(cb & 3, row & 15)) * 8] = v;
  }
  *(uint4*)sdst0 = r0_;
  *(uint4*)(sdst0 + 2048) = r1_;
  gload2(gptr + gstep);
  gptr += 2 * gstep;
  __syncthreads();

  const int rslot = SLOT(quad, l15) * 8;   // reader offset within a K/Q panel

  short8 qf[2][2];
#pragma unroll
  for (int mf = 0; mf < 2; ++mf)
#pragma unroll
    for (int kt = 0; kt < 2; ++kt)
      qf[mf][kt] = *(const short8*)&sQ[(((w * 2 + mf) * 2 + kt) * 64) * 8 + rslot];

  if (!part) s_allones = 0;
  __syncthreads();
  const int allones = s_allones;

  float lsum[2] = {0.f, 0.f};
  f32x4 accOT[2][4];   // O^T: [mf][n], col q=l15, rows d = n*16 + quad*4 + r
#pragma unroll
  for (int i = 0; i < 2; ++i)
#pragma unroll
    for (int j = 0; j < 4; ++j) accOT[i][j] = (f32x4){0.f, 0.f, 0.f, 0.f};

  for (int t = 0; t < 32; ++t) {
    if (t) __syncthreads();
    const int buf = t & 1;
    if (t < 31) {
      u16* d = (t & 1) ? sdst0 : sdst1;   // tile t+1 -> buf (t+1)&1
      *(uint4*)d = r0_;
      *(uint4*)(d + 2048) = r1_;
      if (t < 30) {
        gload2(gptr);
        gptr += gstep;
      }
    }
    // scores: Sc^T[kv 64][q 32/wave]; accS[mk] holds kv rows mk*16+quad*4+r
    f32x4 accS[4][2];
#pragma unroll
    for (int i = 0; i < 4; ++i)
#pragma unroll
      for (int j = 0; j < 2; ++j) accS[i][j] = (f32x4){0.f, 0.f, 0.f, 0.f};
#pragma unroll
    for (int kt = 0; kt < 2; ++kt) {
      short8 kf[4];
#pragma unroll
      for (int mk = 0; mk < 4; ++mk)
        kf[mk] = *(const short8*)&sK[buf][((mk * 2 + kt) * 64) * 8 + rslot];
#pragma unroll
      for (int mk = 0; mk < 4; ++mk)
#pragma unroll
        for (int mf = 0; mf < 2; ++mf)
          accS[mk][mf] = __builtin_amdgcn_mfma_f32_16x16x32_bf16(kf[mk], qf[mf][kt], accS[mk][mf], 0, 0, 0);
    }
    // softmax numerator -> P^T bf16, in registers (k=quad*4+r layout)
    s16x4 pb[4][2];
    if (allones) {
#pragma unroll
      for (int mk = 0; mk < 4; ++mk)
#pragma unroll
        for (int mf = 0; mf < 2; ++mf) {
          float p0 = __builtin_amdgcn_exp2f(accS[mk][mf][0]);
          float p1 = __builtin_amdgcn_exp2f(accS[mk][mf][1]);
          float p2 = __builtin_amdgcn_exp2f(accS[mk][mf][2]);
          float p3 = __builtin_amdgcn_exp2f(accS[mk][mf][3]);
          lsum[mf] += (p0 + p1) + (p2 + p3);
          *(uint2*)&pb[mk][mf] = make_uint2(pk2bf(p0, p1), pk2bf(p2, p3));
        }
    } else {
#pragma unroll
      for (int mk = 0; mk < 4; ++mk) {
        const int4 mv = *(const int4*)(maskg + t * 64 + mk * 16 + quad * 4);
#pragma unroll
        for (int mf = 0; mf < 2; ++mf) {
          float p0 = mv.x ? __builtin_amdgcn_exp2f(accS[mk][mf][0]) : 0.f;
          float p1 = mv.y ? __builtin_amdgcn_exp2f(accS[mk][mf][1]) : 0.f;
          float p2 = mv.z ? __builtin_amdgcn_exp2f(accS[mk][mf][2]) : 0.f;
          float p3 = mv.w ? __builtin_amdgcn_exp2f(accS[mk][mf][3]) : 0.f;
          lsum[mf] += (p0 + p1) + (p2 + p3);
          *(uint2*)&pb[mk][mf] = make_uint2(pk2bf(p0, p1), pk2bf(p2, p3));
        }
      }
    }
    // PV: O^T[d 64][q 32] += V^T @ P^T via K=16 MFMA
#pragma unroll
    for (int kp = 0; kp < 2; ++kp) {
#pragma unroll
      for (int n = 0; n < 4; ++n) {
        short8 vv = *(const short8*)&sV[buf][(kp * 256 + n * 64 + lane) * 8];
        s16x4 v0 = __builtin_shufflevector(vv, vv, 0, 1, 2, 3);
        s16x4 v1 = __builtin_shufflevector(vv, vv, 4, 5, 6, 7);
#pragma unroll
        for (int mf = 0; mf < 2; ++mf) {
          accOT[mf][n] = mfma16(v0, pb[kp * 2][mf], accOT[mf][n]);
          accOT[mf][n] = mfma16(v1, pb[kp * 2 + 1][mf], accOT[mf][n]);
        }
      }
    }
  }

  // epilogue: lsum reduce over quads; O^T cols share q=l15 -> per-lane inv
#pragma unroll
  for (int mf = 0; mf < 2; ++mf) {
    lsum[mf] += __shfl_xor(lsum[mf], 16, 64);
    lsum[mf] += __shfl_xor(lsum[mf], 32, 64);
  }
  const float inv0 = 1.f / lsum[0], inv1 = 1.f / lsum[1];
#pragma unroll
  for (int mf = 0; mf < 2; ++mf) {
    const float iv = mf ? inv1 : inv0;
    u16* cp = ctxg + (long)(w * 32 + mf * 16 + l15) * D_;
#pragma unroll
    for (int n = 0; n < 4; ++n) {
      float o0 = accOT[mf][n][0] * iv;
      float o1 = accOT[mf][n][1] * iv;
      float o2 = accOT[mf][n][2] * iv;
      float o3 = accOT[mf][n][3] * iv;
      *(uint2*)(cp + n * 16 + quad * 4) = make_uint2(pk2bf(o0, o1), pk2bf(o2, o3));
    }
  }
}

// ---------------- add + layernorm helpers ----------------
__device__ __forceinline__ float block_reduce_sum(float v, float* red) {
#pragma unroll
  for (int off = 32; off; off >>= 1) v += __shfl_down(v, off, 64);
  __syncthreads();
  if ((threadIdx.x & 63) == 0) red[threadIdx.x >> 6] = v;
  __syncthreads();
  return red[0] + red[1] + red[2] + red[3];
}

// x (fp32) + mha0 + mha1 (bf16 split-K partials) + bo -> LN -> x1 (bf16)
__global__ __launch_bounds__(256) void addln_fb(const float* __restrict__ A,
    const u16* __restrict__ M0, const u16* __restrict__ M1, const float* __restrict__ bo,
    const float* __restrict__ g, const float* __restrict__ be, u16* __restrict__ outp) {
  __shared__ float red[4];
  const int row = blockIdx.x, tid = threadIdx.x;
  const float4 av = ((const float4*)(A + (long)row * D_))[tid];
  const uint2 m0 = ((const uint2*)(M0 + (long)row * D_))[tid];
  const uint2 m1 = ((const uint2*)(M1 + (long)row * D_))[tid];
  const int c0 = tid * 4;
  float xv[4];
  xv[0] = av.x + bf2f((u16)(m0.x & 0xffff)) + bf2f((u16)(m1.x & 0xffff)) + bo[c0 + 0];
  xv[1] = av.y + bf2f((u16)(m0.x >> 16))    + bf2f((u16)(m1.x >> 16))    + bo[c0 + 1];
  xv[2] = av.z + bf2f((u16)(m0.y & 0xffff)) + bf2f((u16)(m1.y & 0xffff)) + bo[c0 + 2];
  xv[3] = av.w + bf2f((u16)(m0.y >> 16))    + bf2f((u16)(m1.y >> 16))    + bo[c0 + 3];
  float s  = xv[0] + xv[1] + xv[2] + xv[3];
  float ss = xv[0]*xv[0] + xv[1]*xv[1] + xv[2]*xv[2] + xv[3]*xv[3];
  s  = block_reduce_sum(s, red);
  ss = block_reduce_sum(ss, red);
  const float m   = s * (1.0f / 1024.0f);
  const float var = ss * (1.0f / 1024.0f) - m * m;
  const float rs  = rsqrtf(var + 1e-5f);
  float v0 = (xv[0] - m) * rs * g[c0 + 0] + be[c0 + 0];
  float v1 = (xv[1] - m) * rs * g[c0 + 1] + be[c0 + 1];
  float v2 = (xv[2] - m) * rs * g[c0 + 2] + be[c0 + 2];
  float v3 = (xv[3] - m) * rs * g[c0 + 3] + be[c0 + 3];
  unsigned int o01 = (unsigned int)f2bf(v0) | ((unsigned int)f2bf(v1) << 16);
  unsigned int o23 = (unsigned int)f2bf(v2) | ((unsigned int)f2bf(v3) << 16);
  ((uint2*)(outp + (long)row * D_))[tid] = make_uint2(o01, o23);
}

// x1 (bf16) + ff0..ff3 (bf16 split-K partials) + b2 -> LN -> out (fp32)
__global__ __launch_bounds__(256) void addln2_bf(const u16* __restrict__ A,
    const u16* __restrict__ F0, const u16* __restrict__ F1,
    const u16* __restrict__ F2, const u16* __restrict__ F3,
    const float* __restrict__ b2,
    const float* __restrict__ g, const float* __restrict__ be, float* __restrict__ outp) {
  __shared__ float red[4];
  const int row = blockIdx.x, tid = threadIdx.x;
  const uint2 av = ((const uint2*)(A + (long)row * D_))[tid];
  const uint2 f0 = ((const uint2*)(F0 + (long)row * D_))[tid];
  const uint2 f1 = ((const uint2*)(F1 + (long)row * D_))[tid];
  const uint2 f2 = ((const uint2*)(F2 + (long)row * D_))[tid];
  const uint2 f3 = ((const uint2*)(F3 + (long)row * D_))[tid];
  const int c0 = tid * 4;
  float xv[4];
  xv[0] = bf2f((u16)(av.x & 0xffff)) + bf2f((u16)(f0.x & 0xffff)) + bf2f((u16)(f1.x & 0xffff))
        + bf2f((u16)(f2.x & 0xffff)) + bf2f((u16)(f3.x & 0xffff)) + b2[c0 + 0];
  xv[1] = bf2f((u16)(av.x >> 16))    + bf2f((u16)(f0.x >> 16))    + bf2f((u16)(f1.x >> 16))
        + bf2f((u16)(f2.x >> 16))    + bf2f((u16)(f3.x >> 16))    + b2[c0 + 1];
  xv[2] = bf2f((u16)(av.y & 0xffff)) + bf2f((u16)(f0.y & 0xffff)) + bf2f((u16)(f1.y & 0xffff))
        + bf2f((u16)(f2.y & 0xffff)) + bf2f((u16)(f3.y & 0xffff)) + b2[c0 + 2];
  xv[3] = bf2f((u16)(av.y >> 16))    + bf2f((u16)(f0.y >> 16))    + bf2f((u16)(f1.y >> 16))
        + bf2f((u16)(f2.y >> 16))    + bf2f((u16)(f3.y >> 16))    + b2[c0 + 3];
  float s  = xv[0] + xv[1] + xv[2] + xv[3];
  float ss = xv[0]*xv[0] + xv[1]*xv[1] + xv[2]*xv[2] + xv[3]*xv[3];
  s  = block_reduce_sum(s, red);
  ss = block_reduce_sum(ss, red);
  const float m   = s * (1.0f / 1024.0f);
  const float var = ss * (1.0f / 1024.0f) - m * m;
  const float rs  = rsqrtf(var + 1e-5f);
  float4 o;
  o.x = (xv[0] - m) * rs * g[c0 + 0] + be[c0 + 0];
  o.y = (xv[1] - m) * rs * g[c0 + 1] + be[c0 + 1];
  o.z = (xv[2] - m) * rs * g[c0 + 2] + be[c0 + 2];
  o.w = (xv[3] - m) * rs * g[c0 + 3] + be[c0 + 3];
  ((float4*)(outp + (long)row * D_))[tid] = o;
}

extern "C" void kernel_launch(void* const* d_in, const int* in_sizes, int n_in,
                              void* d_out, int out_size, void* d_ws, size_t ws_size,
                              hipStream_t stream) {
  const float* x   = (const float*)d_in[0];
  const float* y   = (const float*)d_in[1];
  const int* mask  = (const int*)d_in[2];
  const float* Wq = (const float*)d_in[3];  const float* bq = (const float*)d_in[4];
  const float* Wk = (const float*)d_in[5];  const float* bk = (const float*)d_in[6];
  const float* Wv = (const float*)d_in[7];  const float* bv = (const float*)d_in[8];
  const float* Wo = (const float*)d_in[9];  const float* bo = (const float*)d_in[10];
  const float* W1 = (const float*)d_in[11]; const float* b1 = (const float*)d_in[12];
  const float* W2 = (const float*)d_in[13]; const float* b2 = (const float*)d_in[14];
  const float* g1 = (const float*)d_in[15]; const float* be1 = (const float*)d_in[16];
  const float* g2 = (const float*)d_in[17]; const float* be2 = (const float*)d_in[18];
  float* out = (float*)d_out;

  char* w = (char*)d_ws;
  const size_t MB = 1024 * 1024;
  u16* WqT = (u16*)(w + 0 * MB);
  u16* WkT = (u16*)(w + 2 * MB);
  u16* WvT = (u16*)(w + 4 * MB);
  u16* WoT = (u16*)(w + 6 * MB);
  u16* W1T = (u16*)(w + 8 * MB);     // 8MB  [HID][D]
  u16* W2T = (u16*)(w + 16 * MB);    // 8MB  [D][HID]
  u16* xb  = (u16*)(w + 24 * MB);    // dead after qkv; x1 reuses
  u16* yb  = (u16*)(w + 32 * MB);    // dead after qkv
  u16* Q   = (u16*)(w + 40 * MB);    // dead after flash; ff partials reuse
  u16* Kp  = (u16*)(w + 48 * MB);    // dead after flash
  u16* Vp  = (u16*)(w + 56 * MB);    // dead after vtrans
  u16* Vt  = (u16*)(w + 64 * MB);    // dead after flash
  u16* ctx = (u16*)(w + 72 * MB);    // dead after Wo gemm
  u16* mha = (u16*)(w + 80 * MB);    // 2 x 8MB bf16 split-K partials (80..96)
  u16* x1  = (u16*)(w + 24 * MB);    // reuses xb; live through addln2
  u16* h1  = (u16*)(w + 96 * MB);    // 32MB bf16 [4096][4096]
  u16* ff  = (u16*)(w + 40 * MB);    // 4 x 8MB bf16 split-K partials (40..72)

  // prep: 6 weight transposes + 2 activation cvts, ONE dispatch
  prep8_k<<<dim3(128, 32, 8), dim3(32, 8), 0, stream>>>(Wq, Wk, Wv, Wo, W1, W2,
      x, y, WqT, WkT, WvT, WoT, W1T, W2T, xb, yb);

  // QKV: m97 structure, 768 blocks (high TLP wins at skinny N; R2 post-mortem)
  qkv_k<<<dim3(8, 32, 3), 256, 0, stream>>>(xb, yb, WqT, WkT, WvT, bq, bk, bv, Q, Kp, Vp);

  vtrans_k<<<dim3(64, 2, 32), dim3(32, 8), 0, stream>>>(Vp, Vt);

  // fused flash attention v9: QBLK=256, KVBLK=64, 256 blocks (1/CU)
  flash_k<<<dim3(32, 8), 512, 0, stream>>>(Q, Kp, Vt, mask, ctx);

  // output projection: split-K=2 on gemm_bt (512 blocks); bo folded into LN1
  gemm_bt<4, 4, 0><<<dim3(8, 32, 2), 256, 0, stream>>>(ctx, WoT, nullptr, mha,
      512, 1024, 1024, 1024, 512, 512, (long)4096 * 1024, 0);
  addln_fb<<<dim3(4096), 256, 0, stream>>>(x, mha, mha + (long)4096 * 1024, bo, g1, be1, x1);

  // FFN1: 256 blocks, 8-phase 256x256 pipeline, relu+bias
  gemm8p_k<1><<<dim3(16, 16, 1), 512, 0, stream>>>(x1, W1T, b1, h1,
      1024, 1024, 1024, 4096, 0, 0);
  // FFN2: split-K=4 on the 8-phase pipeline (256 blocks); b2 folded into LN2
  gemm8p_k<0><<<dim3(4, 16, 4), 512, 0, stream>>>(h1, W2T, nullptr, ff,
      1024, 4096, 4096, 1024, 1024, (long)4096 * 1024);
  addln2_bf<<<dim3(4096), 256, 0, stream>>>(x1, ff, ff + (long)4096 * 1024,
      ff + (long)2 * 4096 * 1024, ff + (long)3 * 4096 * 1024, b2, g2, be2, out);
}